// Round 9
// baseline (321.793 us; speedup 1.0000x reference)
//
#include <hip/hip_runtime.h>
#include <hip/hip_bf16.h>
#include <math.h>

#define B 64
#define L 400
#define IN_DIM 500
#define D 128
#define H 8
#define HD 16
#define NCONV 4
#define BL (B*L)

typedef __attribute__((ext_vector_type(8))) unsigned short ushort8;
typedef __attribute__((ext_vector_type(8))) short bf16x8;
typedef __attribute__((ext_vector_type(4))) float f32x4;

__device__ __forceinline__ unsigned short f2bf(float f) {
    unsigned u = __float_as_uint(f);
    unsigned r = (u + 0x7fffu + ((u >> 16) & 1u)) >> 16;
    return (unsigned short)r;
}
__device__ __forceinline__ float bf2f(unsigned short u) {
    return __uint_as_float(((unsigned)u) << 16);
}
__device__ __forceinline__ unsigned cvtpk_bf16(float lo, float hi) {
    unsigned r;
    asm("v_cvt_pk_bf16_f32 %0, %1, %2" : "=v"(r) : "v"(lo), "v"(hi));
    return r;
}

__device__ __forceinline__ void gload16(const void* g, void* l) {
    __builtin_amdgcn_global_load_lds(
        (const __attribute__((address_space(1))) unsigned int*)g,
        (__attribute__((address_space(3))) unsigned int*)l,
        16, 0, 0);
}

// ---------------------------------------------------------------------------
// Merged pre-pass: [0,6464) cvt_x; [6464,7744) cvt_w; [7744,8384) cvt_wall.
// ---------------------------------------------------------------------------
__global__ __launch_bounds__(256) void k_cvt_all(
        const float* __restrict__ x, unsigned short* __restrict__ xb,
        const float* __restrict__ w_init, unsigned short* __restrict__ wbt,
        const float* __restrict__ w_pw, const float* __restrict__ wq,
        const float* __restrict__ wk, const float* __restrict__ wv,
        const float* __restrict__ wo, const float* __restrict__ w1,
        const float* __restrict__ w2, unsigned short* __restrict__ wt) {
    int bid = blockIdx.x;
    if (bid < 6464) {
        int idx = bid * 256 + threadIdx.x;   // chunk of 8 bf16
        int row = idx >> 6, ch = idx & 63;
        int b = row / 404, rr = row - b * 404;
        ushort8 o = (ushort8)0;
        if (rr >= 2 && rr < 402) {
            int l = rr - 2;
            const float* src = x + ((size_t)b * 400 + l) * 500 + ch * 8;
            if (ch < 62) {
                float4 v0 = *(const float4*)(src);
                float4 v1 = *(const float4*)(src + 4);
                o[0] = f2bf(v0.x); o[1] = f2bf(v0.y); o[2] = f2bf(v0.z); o[3] = f2bf(v0.w);
                o[4] = f2bf(v1.x); o[5] = f2bf(v1.y); o[6] = f2bf(v1.z); o[7] = f2bf(v1.w);
            } else {
#pragma unroll
                for (int j = 0; j < 8; ++j) {
                    int c = ch * 8 + j;
                    o[j] = (c < 500) ? f2bf(src[j]) : (unsigned short)0;
                }
            }
        }
        *(ushort8*)(xb + (size_t)idx * 8) = o;
    } else if (bid < 7744) {
        int idx = (bid - 6464) * 256 + threadIdx.x;
        int k = idx & 511, n = (idx >> 9) & 127, t = idx >> 16;
        float v = (k < 500) ? w_init[((size_t)t * 500 + k) * 128 + n] : 0.f;
        wbt[idx] = f2bf(v);
    } else {
        int rb = bid - 7744;
        const float* arr[10] = {w_pw, w_pw + 16384, w_pw + 2 * 16384,
                                w_pw + 3 * 16384, wq, wk, wv, wo, w1, w2};
        int widx = rb >> 6;
        const float* w = arr[widx];
        int idx = ((rb & 63) << 8) + threadIdx.x;
        int n = idx >> 7, k = idx & 127;
        wt[(size_t)widx * 16384 + idx] = f2bf(w[k * 128 + n]);
    }
}

// ---------------------------------------------------------------------------
// Kernel 1: init conv MFMA, taps fused behind one barrier pair per k0.
// ---------------------------------------------------------------------------
#define TM 80
#define BK 64
__global__ __launch_bounds__(256) void k_initconv_mfma(
        const unsigned short* __restrict__ xb,
        const unsigned short* __restrict__ wbt,
        const float* __restrict__ bias, float* __restrict__ out) {
    __shared__ unsigned short As[84 * BK];        // 10.5 KB (rows l0..l0+83)
    __shared__ unsigned short Ws[5][64 * BK];     // 40 KB  (5 taps x 64n x 64k)
    int tid = threadIdx.x;
    int b = blockIdx.x / 10;
    int rem = blockIdx.x - b * 10;
    int l0 = (rem >> 1) * TM;
    int nh = rem & 1;
    int lane = tid & 63, wave = tid >> 6;
    int kgrp = lane >> 4, lm = lane & 15;

    f32x4 acc[5];
#pragma unroll
    for (int mf = 0; mf < 5; ++mf) acc[mf] = (f32x4)0.f;

    const unsigned short* abase = xb + ((size_t)(b * 404 + l0)) * 512;
    const unsigned short* wbase = wbt + (size_t)nh * 64 * 512;

    for (int k0 = 0; k0 < 512; k0 += BK) {
        for (int idx = tid; idx < 672; idx += 256) {
            int r = idx >> 3, sc = idx & 7;
            gload16(abase + (size_t)r * 512 + k0 + ((sc ^ (r & 7)) * 8),
                    As + idx * 8);
        }
#pragma unroll
        for (int i = 0; i < 10; ++i) {
            int idx = tid + i * 256;
            int t = idx >> 9;          // 0..4
            int sub = idx & 511;
            int n = sub >> 3, sc = sub & 7;
            gload16(wbase + (size_t)t * 128 * 512 + (size_t)n * 512 + k0
                        + ((sc ^ (n & 7)) * 8),
                    &Ws[t][0] + sub * 8);
        }
        __syncthreads();
        int n16 = wave * 16 + lm;
#pragma unroll
        for (int ks = 0; ks < 2; ++ks) {
            int gc = ks * 4 + kgrp;
            bf16x8 bfr[5];
#pragma unroll
            for (int t = 0; t < 5; ++t)
                bfr[t] = *(const bf16x8*)(&Ws[t][0] + n16 * 64
                                          + ((gc ^ (n16 & 7)) * 8));
#pragma unroll
            for (int mf = 0; mf < 5; ++mf) {
#pragma unroll
                for (int t = 0; t < 5; ++t) {
                    int r = mf * 16 + lm + t;
                    bf16x8 af = *(const bf16x8*)(As + r * 64
                                                 + ((gc ^ (r & 7)) * 8));
                    acc[mf] = __builtin_amdgcn_mfma_f32_16x16x32_bf16(
                        af, bfr[t], acc[mf], 0, 0, 0);
                }
            }
        }
        __syncthreads();
    }

    {
        int n = nh * 64 + wave * 16 + lm;
        float bs = bias[n];
        float pbase = expf(-(float)(n & ~1) * (9.210340371976184f / 128.0f));
#pragma unroll
        for (int mf = 0; mf < 5; ++mf) {
#pragma unroll
            for (int r = 0; r < 4; ++r) {
                int l = l0 + mf * 16 + kgrp * 4 + r;
                float ang = (float)l * pbase;
                float pe = (n & 1) ? cosf(ang) : sinf(ang);
                out[((size_t)b * 400 + l) * 128 + n] = acc[mf][r] + bs + pe;
            }
        }
    }
}

// ---------------------------------------------------------------------------
// Kernel 2: fused conv block: pre-LN + depthwise k=7 + pointwise GEMM
// + relu + residual, one HBM round-trip. Grid 832 = 64 b x 13 tiles of 32 l.
// ---------------------------------------------------------------------------
#define CB_ROWS 38
__global__ __launch_bounds__(256) void k_convblock(
        const float* __restrict__ hin, float* __restrict__ hout,
        const float* __restrict__ lng, const float* __restrict__ lnb,
        const float* __restrict__ wdw, const float* __restrict__ bdw,
        const unsigned short* __restrict__ wpt, const float* __restrict__ bpw) {
    __shared__ unsigned short Ws[128 * 128];     // 32 KB pw weight (n-major)
    __shared__ unsigned short Ln[CB_ROWS * 128]; // 9.5 KB LN'd rows (plain)
    __shared__ unsigned short Dw[32 * 128];      // 8 KB dw out (swizzled A)
    int tid = threadIdx.x;
    int b = blockIdx.x / 13;
    int tile = blockIdx.x - b * 13;
    int l0 = tile * 32;
    int lv = (l0 + 32 <= L) ? 32 : (L - l0);
    int lane = tid & 63, wave = tid >> 6;
    int lm = lane & 15, kgrp = lane >> 4;

    // stage pointwise weight early (overlaps LN compute)
#pragma unroll
    for (int i = 0; i < 8; ++i) {
        int idx = tid + i * 256;
        int n = idx >> 4, sc = idx & 15;
        gload16(wpt + (size_t)n * 128 + ((sc ^ (n & 15)) * 8), Ws + idx * 8);
    }

    // LN phase: rows l0-3 .. l0+34, one wave per row (strided by 4)
    {
        float2 gg = *(const float2*)(lng + lane * 2);
        float2 bb = *(const float2*)(lnb + lane * 2);
#pragma unroll
        for (int ri = 0; ri < 10; ++ri) {
            int r = wave + ri * 4;
            if (r < CB_ROWS) {
                int gl = l0 - 3 + r;
                bool ok = (gl >= 0 && gl < L);
                float2 v = make_float2(0.f, 0.f);
                if (ok) v = *(const float2*)(hin + ((size_t)b * L + gl) * 128 + lane * 2);
                float s = v.x + v.y;
                float q = v.x * v.x + v.y * v.y;
#pragma unroll
                for (int off = 32; off; off >>= 1) {
                    s += __shfl_xor(s, off);
                    q += __shfl_xor(q, off);
                }
                float mu  = s * (1.f / 128.f);
                float var = q * (1.f / 128.f) - mu * mu;
                float inv = rsqrtf(var + 1e-5f);
                unsigned pk = 0;
                if (ok) {
                    float ox = (v.x - mu) * inv * gg.x + bb.x;
                    float oy = (v.y - mu) * inv * gg.y + bb.y;
                    pk = (unsigned)f2bf(ox) | ((unsigned)f2bf(oy) << 16);
                }
                *(unsigned*)(Ln + r * 128 + lane * 2) = pk;
            }
        }
    }
    __syncthreads();

    // depthwise conv k=7: thread owns channel d, 16 l rows (rolling window)
    {
        int d = tid & 127, half = tid >> 7;
        float wr[7];
#pragma unroll
        for (int t = 0; t < 7; ++t) wr[t] = wdw[t * 128 + d];
        float bs = bdw[d];
        float win[7];
#pragma unroll
        for (int t = 0; t < 6; ++t) win[t] = bf2f(Ln[(half * 16 + t) * 128 + d]);
#pragma unroll
        for (int lj = 0; lj < 16; ++lj) {
            int l = half * 16 + lj;
            win[6] = bf2f(Ln[(l + 6) * 128 + d]);
            float a = bs;
#pragma unroll
            for (int t = 0; t < 7; ++t) a = fmaf(win[t], wr[t], a);
#pragma unroll
            for (int t = 0; t < 6; ++t) win[t] = win[t + 1];
            Dw[l * 128 + ((d >> 3) ^ (l & 15)) * 8 + (d & 7)] = f2bf(a);
        }
    }
    __syncthreads();

    // pointwise GEMM: [32,128] x [128,128]; wave owns 32-col quarter
    f32x4 acc[2][2];
#pragma unroll
    for (int mf = 0; mf < 2; ++mf)
#pragma unroll
        for (int nt = 0; nt < 2; ++nt) acc[mf][nt] = (f32x4)0.f;
#pragma unroll
    for (int kc = 0; kc < 4; ++kc) {
        int c = kc * 4 + kgrp;
        bf16x8 af[2];
#pragma unroll
        for (int mf = 0; mf < 2; ++mf) {
            int r = mf * 16 + lm;
            af[mf] = *(const bf16x8*)(Dw + r * 128 + (c ^ (r & 15)) * 8);
        }
#pragma unroll
        for (int nt = 0; nt < 2; ++nt) {
            int n = wave * 32 + nt * 16 + lm;
            bf16x8 bfv = *(const bf16x8*)(Ws + n * 128 + (c ^ (n & 15)) * 8);
#pragma unroll
            for (int mf = 0; mf < 2; ++mf)
                acc[mf][nt] = __builtin_amdgcn_mfma_f32_16x16x32_bf16(
                    af[mf], bfv, acc[mf][nt], 0, 0, 0);
        }
    }

    // epilogue: relu(pw + bias) + residual
#pragma unroll
    for (int nt = 0; nt < 2; ++nt) {
        int n = wave * 32 + nt * 16 + lm;
        float bsn = bpw[n];
#pragma unroll
        for (int mf = 0; mf < 2; ++mf) {
#pragma unroll
            for (int r = 0; r < 4; ++r) {
                int row = mf * 16 + kgrp * 4 + r;
                if (row < lv) {
                    size_t gi = ((size_t)b * L + l0 + row) * 128 + n;
                    hout[gi] = fmaxf(acc[mf][nt][r] + bsn, 0.f) + hin[gi];
                }
            }
        }
    }
}

// ---------------------------------------------------------------------------
// Kernel 3: fused LN + GEMM(s). (QKV: nw=3, FFN1: nw=1.)
// ---------------------------------------------------------------------------
__global__ __launch_bounds__(256) void k_ln_gemm(
        const float* __restrict__ h, const float* __restrict__ g,
        const float* __restrict__ bta, const unsigned short* __restrict__ wt0,
        int nw, const float* __restrict__ bias0, const float* __restrict__ bias1,
        const float* __restrict__ bias2, unsigned short* __restrict__ out0,
        unsigned short* __restrict__ out1, unsigned short* __restrict__ out2,
        float s0, int relu) {
    __shared__ unsigned short As[32 * 128];   // 8 KB
    __shared__ unsigned short Ws[128 * 128];  // 32 KB
    int tid = threadIdx.x;
    int m0 = blockIdx.x * 32;
    int lane = tid & 63, wave = tid >> 6;
    int lm = lane & 15, kgrp = lane >> 4;
    int wm = wave >> 1, wn = wave & 1;

#pragma unroll
    for (int i = 0; i < 8; ++i) {
        int idx = tid + i * 256;
        int n = idx >> 4, sc = idx & 15;
        gload16(wt0 + (size_t)n * 128 + ((sc ^ (n & 15)) * 8), Ws + idx * 8);
    }

    {
        float2 gg = *(const float2*)(g + lane * 2);
        float2 bb = *(const float2*)(bta + lane * 2);
#pragma unroll
        for (int ri = 0; ri < 8; ++ri) {
            int r = wave + ri * 4;
            float2 v = *(const float2*)(h + ((size_t)m0 + r) * 128 + lane * 2);
            float s = v.x + v.y;
            float q = v.x * v.x + v.y * v.y;
#pragma unroll
            for (int off = 32; off; off >>= 1) {
                s += __shfl_xor(s, off);
                q += __shfl_xor(q, off);
            }
            float mu  = s * (1.f / 128.f);
            float var = q * (1.f / 128.f) - mu * mu;
            float inv = rsqrtf(var + 1e-5f);
            float ox = (v.x - mu) * inv * gg.x + bb.x;
            float oy = (v.y - mu) * inv * gg.y + bb.y;
            unsigned pk = (unsigned)f2bf(ox) | ((unsigned)f2bf(oy) << 16);
            *(unsigned*)(As + r * 128 + ((lane >> 2) ^ (r & 15)) * 8
                         + ((lane * 2) & 7)) = pk;
        }
    }

    for (int i = 0; i < nw; ++i) {
        __syncthreads();
        f32x4 acc[4];
#pragma unroll
        for (int nt = 0; nt < 4; ++nt) acc[nt] = (f32x4)0.f;
#pragma unroll
        for (int kc = 0; kc < 4; ++kc) {
            int c = kc * 4 + kgrp;
            int r = wm * 16 + lm;
            bf16x8 af = *(const bf16x8*)(As + r * 128 + (c ^ (r & 15)) * 8);
#pragma unroll
            for (int nt = 0; nt < 4; ++nt) {
                int n = wn * 64 + nt * 16 + lm;
                bf16x8 bfv = *(const bf16x8*)(Ws + n * 128 + (c ^ (n & 15)) * 8);
                acc[nt] = __builtin_amdgcn_mfma_f32_16x16x32_bf16(
                    af, bfv, acc[nt], 0, 0, 0);
            }
        }
        const float* bias = (i == 0) ? bias0 : (i == 1) ? bias1 : bias2;
        unsigned short* out = (i == 0) ? out0 : (i == 1) ? out1 : out2;
        float sc0 = (i == 0) ? s0 : 1.f;
#pragma unroll
        for (int nt = 0; nt < 4; ++nt) {
            int n = wn * 64 + nt * 16 + lm;
            float bsn = bias[n];
#pragma unroll
            for (int r = 0; r < 4; ++r) {
                size_t m = (size_t)m0 + wm * 16 + kgrp * 4 + r;
                float v = acc[nt][r] + bsn;
                if (relu) v = fmaxf(v, 0.f);
                out[m * 128 + n] = f2bf(v * sc0);
            }
        }
        if (i + 1 < nw) {
            __syncthreads();
            const unsigned short* wp = wt0 + (size_t)(i + 1) * 16384;
#pragma unroll
            for (int j = 0; j < 8; ++j) {
                int idx = tid + j * 256;
                int n = idx >> 4, sc = idx & 15;
                gload16(wp + (size_t)n * 128 + ((sc ^ (n & 15)) * 8), Ws + idx * 8);
            }
        }
    }
}

// ---------------------------------------------------------------------------
// Kernel 4: bf16 MFMA GEMM, 32m x 128n tiles (o-proj, FFN2).
// ---------------------------------------------------------------------------
__global__ __launch_bounds__(256) void k_gemm_bf16(
        const unsigned short* __restrict__ A,
        const unsigned short* __restrict__ Wt,
        const float* __restrict__ bias,
        const float* __restrict__ res,
        float* __restrict__ outf,
        unsigned short* __restrict__ outb,
        int relu, float oscale) {
    __shared__ unsigned short As[32 * 128];   // 8 KB
    __shared__ unsigned short Ws[128 * 128];  // 32 KB
    int tid = threadIdx.x;
    int m0 = blockIdx.x * 32;
    int lane = tid & 63, wave = tid >> 6;
    int lm = lane & 15, kgrp = lane >> 4;
    int wm = wave >> 1, wn = wave & 1;

#pragma unroll
    for (int i = 0; i < 2; ++i) {
        int idx = tid + i * 256;
        int r = idx >> 4, sc = idx & 15;
        gload16(A + ((size_t)(m0 + r)) * 128 + ((sc ^ (r & 15)) * 8), As + idx * 8);
    }
#pragma unroll
    for (int i = 0; i < 8; ++i) {
        int idx = tid + i * 256;
        int n = idx >> 4, sc = idx & 15;
        gload16(Wt + ((size_t)n) * 128 + ((sc ^ (n & 15)) * 8), Ws + idx * 8);
    }
    __syncthreads();

    f32x4 acc[4];
#pragma unroll
    for (int nt = 0; nt < 4; ++nt) acc[nt] = (f32x4)0.f;

#pragma unroll
    for (int kc = 0; kc < 4; ++kc) {
        int c = kc * 4 + kgrp;
        int r = wm * 16 + lm;
        bf16x8 af = *(const bf16x8*)(As + (r * 16 + (c ^ (r & 15))) * 8);
#pragma unroll
        for (int nt = 0; nt < 4; ++nt) {
            int n = wn * 64 + nt * 16 + lm;
            bf16x8 bfv = *(const bf16x8*)(Ws + (n * 16 + (c ^ (n & 15))) * 8);
            acc[nt] = __builtin_amdgcn_mfma_f32_16x16x32_bf16(af, bfv, acc[nt], 0, 0, 0);
        }
    }

#pragma unroll
    for (int nt = 0; nt < 4; ++nt) {
        int n = wn * 64 + nt * 16 + lm;
        float bs = bias[n];
#pragma unroll
        for (int r = 0; r < 4; ++r) {
            size_t m = (size_t)m0 + wm * 16 + kgrp * 4 + r;
            float v = acc[nt][r] + bs;
            if (relu) v = fmaxf(v, 0.f);
            if (res)  v += res[m * 128 + n];
            if (outf) outf[m * 128 + n] = v;
            else      outb[m * 128 + n] = f2bf(v * oscale);
        }
    }
}

// ---------------------------------------------------------------------------
// Kernel 5 v6: swapped QK^T (R2-verified) + LDS P-bounce (R3/R7-verified).
// Token-major staging + XCD swizzle exactly as R7 (passing).
// Lane (lm,g) holds S[k=kt*16+g*4+r][q=lm]: softmax = lane-local + 2 shfl;
// exp fused into PV; P packed via 2x v_cvt_pk_bf16_f32 -> one 8B LDS write
// per (lane,kt). P row=lm(q), col=t*16+g*4+r(k) -> PV reads Pf unchanged.
// ---------------------------------------------------------------------------
#define KS 40
#define VS 424
__global__ __launch_bounds__(512) void k_attn_mfma(
        const unsigned short* __restrict__ qb,
        const unsigned short* __restrict__ kb,
        const unsigned short* __restrict__ vb,
        unsigned short* __restrict__ out) {
    __shared__ __align__(16) unsigned short Kpad[400 * KS];
    __shared__ __align__(16) unsigned short Vt[16 * VS];
    __shared__ __align__(16) unsigned short Ptmp[8][16 * KS];
    int tid = threadIdx.x;
    int b = blockIdx.x & 63, h = blockIdx.x >> 6;   // XCD-grouping swizzle (R7)
    int lane = tid & 63, wave = tid >> 6;
    int lm = lane & 15, g = lane >> 4;

    for (int idx = tid; idx < 800; idx += 512) {
        int l = idx >> 1, half = idx & 1;
        ushort8 kv = *(const ushort8*)(kb + ((size_t)(b * 400 + l)) * 128 + h * 16 + half * 8);
        *(ushort8*)(Kpad + l * KS + half * 8) = kv;
        *(ushort8*)(Kpad + l * KS + 16 + half * 8) = (ushort8)0;
    }
    for (int idx = tid; idx < 800; idx += 512) {
        int kk = idx >> 1, dh = idx & 1;
        ushort8 vv = *(const ushort8*)(vb + ((size_t)(b * 400 + kk)) * 128 + h * 16 + dh * 8);
#pragma unroll
        for (int j = 0; j < 8; ++j) Vt[(dh * 8 + j) * VS + kk] = vv[j];
    }
    if (tid < 256) {
        int d = tid >> 4, kk = 400 + (tid & 15);
        Vt[d * VS + kk] = 0;
    }
    __syncthreads();

    unsigned short* Pw = Ptmp[wave];
    for (int tt = wave; tt < 25; tt += 8) {
        int q0 = tt * 16;
        // Q as B-operand: col=lm=q, k-slot=g*8+j=d (d>=16 garbage x Kpad zeros)
        bf16x8 Qf = *(const bf16x8*)(qb + ((size_t)(b * 400 + q0 + lm)) * 128 + h * 16 + g * 8);
        // swapped QK^T: lane (lm,g) reg r = S[k=kt*16+g*4+r][q=lm]
        f32x4 s[25];
        __builtin_amdgcn_s_setprio(1);
#pragma unroll
        for (int kt = 0; kt < 25; ++kt) {
            bf16x8 Kf = *(const bf16x8*)(Kpad + (kt * 16 + lm) * KS + g * 8);
            s[kt] = __builtin_amdgcn_mfma_f32_16x16x32_bf16(Kf, Qf, (f32x4)0.f, 0, 0, 0);
        }
        __builtin_amdgcn_s_setprio(0);
        // row max for q=lm: lane-local over 100 vals, then xor 16/32
        float m = -1e30f;
#pragma unroll
        for (int kt = 0; kt < 25; ++kt)
            m = fmaxf(m, fmaxf(fmaxf(s[kt][0], s[kt][1]),
                               fmaxf(s[kt][2], s[kt][3])));
        m = fmaxf(m, __shfl_xor(m, 16));
        m = fmaxf(m, __shfl_xor(m, 32));

        // PV with fused exp/pack/sum; write row lm, col t*16 + g*4..g*4+3
        f32x4 O = (f32x4)0.f;
        f32x4 sumv = (f32x4)0.f;
#pragma unroll
        for (int kc = 0; kc < 13; ++kc) {
            {
                int kt = 2 * kc;
                f32x4 p;
                p[0] = __expf(s[kt][0] - m);
                p[1] = __expf(s[kt][1] - m);
                p[2] = __expf(s[kt][2] - m);
                p[3] = __expf(s[kt][3] - m);
                sumv += p;
                uint2 w; w.x = cvtpk_bf16(p[0], p[1]); w.y = cvtpk_bf16(p[2], p[3]);
                *(uint2*)(Pw + lm * KS + g * 4) = w;
            }
            {
                int kt = 2 * kc + 1;
                uint2 w; w.x = 0u; w.y = 0u;
                if (kt < 25) {
                    f32x4 p;
                    p[0] = __expf(s[kt][0] - m);
                    p[1] = __expf(s[kt][1] - m);
                    p[2] = __expf(s[kt][2] - m);
                    p[3] = __expf(s[kt][3] - m);
                    sumv += p;
                    w.x = cvtpk_bf16(p[0], p[1]); w.y = cvtpk_bf16(p[2], p[3]);
                }
                *(uint2*)(Pw + lm * KS + 16 + g * 4) = w;
            }
            __builtin_amdgcn_wave_barrier();
            asm volatile("s_waitcnt lgkmcnt(0)" ::: "memory");
            __builtin_amdgcn_sched_barrier(0);
            bf16x8 Pf = *(const bf16x8*)(Pw + lm * KS + g * 8);
            bf16x8 Vf = *(const bf16x8*)(Vt + lm * VS + kc * 32 + g * 8);
            O = __builtin_amdgcn_mfma_f32_16x16x32_bf16(Pf, Vf, O, 0, 0, 0);
            __builtin_amdgcn_wave_barrier();
        }
        float sum = (sumv[0] + sumv[1]) + (sumv[2] + sumv[3]);
        sum += __shfl_xor(sum, 16);
        sum += __shfl_xor(sum, 32);
        float rinv = 1.f / sum;
        // O[r]: row q = g*4+r, col d = lm; rinv for q lives at lanes lm==q
#pragma unroll
        for (int r = 0; r < 4; ++r) {
            float rq = __shfl(rinv, g * 4 + r);
            int q = q0 + g * 4 + r;
            out[((size_t)(b * 400 + q)) * 128 + h * 16 + lm] = f2bf(O[r] * rq);
        }
    }
}

// ---------------------------------------------------------------------------
extern "C" void kernel_launch(void* const* d_in, const int* in_sizes, int n_in,
                              void* d_out, int out_size, void* d_ws, size_t ws_size,
                              hipStream_t stream) {
    (void)in_sizes; (void)n_in; (void)out_size; (void)ws_size;
    const float* x      = (const float*)d_in[0];
    const float* w_init = (const float*)d_in[1];
    const float* b_init = (const float*)d_in[2];
    const float* lncg   = (const float*)d_in[3];
    const float* lncb   = (const float*)d_in[4];
    const float* w_dw   = (const float*)d_in[5];
    const float* b_dw   = (const float*)d_in[6];
    const float* w_pw   = (const float*)d_in[7];
    const float* b_pw   = (const float*)d_in[8];
    const float* lnag   = (const float*)d_in[9];
    const float* lnab   = (const float*)d_in[10];
    const float* wq     = (const float*)d_in[11];
    const float* bq     = (const float*)d_in[12];
    const float* wk     = (const float*)d_in[13];
    const float* bk     = (const float*)d_in[14];
    const float* wv     = (const float*)d_in[15];
    const float* bv     = (const float*)d_in[16];
    const float* wo     = (const float*)d_in[17];
    const float* bo     = (const float*)d_in[18];
    const float* lnfg   = (const float*)d_in[19];
    const float* lnfb   = (const float*)d_in[20];
    const float* w1     = (const float*)d_in[21];
    const float* b1     = (const float*)d_in[22];
    const float* w2     = (const float*)d_in[23];
    const float* b2     = (const float*)d_in[24];

    float* ws = (float*)d_ws;
    const size_t NBL = (size_t)BL * D;
    float* h0 = ws;
    float* outp = (float*)d_out;

    unsigned short* hnb = (unsigned short*)(ws + NBL);
    unsigned short* t0b = hnb + NBL;
    unsigned short* qb  = t0b + NBL;
    unsigned short* kb  = qb + NBL;
    unsigned short* vb  = kb + NBL;
    unsigned short* wt  = vb + NBL;
    unsigned short* xb  = wt + 10 * 16384;
    unsigned short* wbt = xb + (size_t)64 * 404 * 512;
    float* h1 = (float*)(wbt + (size_t)5 * 128 * 512);   // ping-pong buffer

    // merged pre-pass (x cvt + w_init cvt + 10x weight transpose)
    k_cvt_all<<<8384, 256, 0, stream>>>(x, xb, w_init, wbt,
                                        w_pw, wq, wk, wv, wo, w1, w2, wt);

    // 1) init conv + posenc
    k_initconv_mfma<<<640, 256, 0, stream>>>(xb, wbt, b_init, h0);

    // 2) 4x fused conv blocks, ping-pong h0 <-> h1
    for (int i = 0; i < NCONV; ++i) {
        const float* hin = (i & 1) ? h1 : h0;
        float* hout      = (i & 1) ? h0 : h1;
        k_convblock<<<832, 256, 0, stream>>>(
            hin, hout, lncg + i * D, lncb + i * D,
            w_dw + (size_t)i * 7 * D, b_dw + i * D,
            wt + (size_t)i * 16384, b_pw + i * D);
    }

    // 3) attention: fused LN + QKV (one A-stage, three weights)
    k_ln_gemm<<<800, 256, 0, stream>>>(h0, lnag, lnab, wt + 4 * 16384, 3,
                                       bq, bk, bv, qb, kb, vb, 0.25f, 0);
    k_attn_mfma<<<512, 512, 0, stream>>>(qb, kb, vb, t0b);
    k_gemm_bf16<<<800, 256, 0, stream>>>(t0b, wt + 7 * 16384, bo, h0,
                                         h0, nullptr, 0, 1.f);

    // 4) FFN: fused LN + W1, then W2 + residual
    k_ln_gemm<<<800, 256, 0, stream>>>(h0, lnfg, lnfb, wt + 8 * 16384, 1,
                                       b1, nullptr, nullptr,
                                       t0b, nullptr, nullptr, 1.f, 1);
    k_gemm_bf16<<<800, 256, 0, stream>>>(t0b, wt + 9 * 16384, b2, h0,
                                         outp, nullptr, 0, 1.f);
}

// Round 10
// 308.058 us; speedup vs baseline: 1.0446x; 1.0446x over previous
//
#include <hip/hip_runtime.h>
#include <hip/hip_bf16.h>
#include <math.h>

#define B 64
#define L 400
#define IN_DIM 500
#define D 128
#define H 8
#define HD 16
#define NCONV 4
#define BL (B*L)

typedef __attribute__((ext_vector_type(8))) unsigned short ushort8;
typedef __attribute__((ext_vector_type(8))) short bf16x8;
typedef __attribute__((ext_vector_type(4))) float f32x4;

__device__ __forceinline__ unsigned short f2bf(float f) {
    unsigned u = __float_as_uint(f);
    unsigned r = (u + 0x7fffu + ((u >> 16) & 1u)) >> 16;
    return (unsigned short)r;
}
__device__ __forceinline__ float bf2f(unsigned short u) {
    return __uint_as_float(((unsigned)u) << 16);
}
__device__ __forceinline__ unsigned cvtpk_bf16(float lo, float hi) {
    unsigned r;
    asm("v_cvt_pk_bf16_f32 %0, %1, %2" : "=v"(r) : "v"(lo), "v"(hi));
    return r;
}

__device__ __forceinline__ void gload16(const void* g, void* l) {
    __builtin_amdgcn_global_load_lds(
        (const __attribute__((address_space(1))) unsigned int*)g,
        (__attribute__((address_space(3))) unsigned int*)l,
        16, 0, 0);
}

// ---------------------------------------------------------------------------
// Merged pre-pass: [0,6464) cvt_x; [6464,7744) cvt_w; [7744,8384) cvt_wall.
// ---------------------------------------------------------------------------
__global__ __launch_bounds__(256) void k_cvt_all(
        const float* __restrict__ x, unsigned short* __restrict__ xb,
        const float* __restrict__ w_init, unsigned short* __restrict__ wbt,
        const float* __restrict__ w_pw, const float* __restrict__ wq,
        const float* __restrict__ wk, const float* __restrict__ wv,
        const float* __restrict__ wo, const float* __restrict__ w1,
        const float* __restrict__ w2, unsigned short* __restrict__ wt) {
    int bid = blockIdx.x;
    if (bid < 6464) {
        int idx = bid * 256 + threadIdx.x;   // chunk of 8 bf16
        int row = idx >> 6, ch = idx & 63;
        int b = row / 404, rr = row - b * 404;
        ushort8 o = (ushort8)0;
        if (rr >= 2 && rr < 402) {
            int l = rr - 2;
            const float* src = x + ((size_t)b * 400 + l) * 500 + ch * 8;
            if (ch < 62) {
                float4 v0 = *(const float4*)(src);
                float4 v1 = *(const float4*)(src + 4);
                o[0] = f2bf(v0.x); o[1] = f2bf(v0.y); o[2] = f2bf(v0.z); o[3] = f2bf(v0.w);
                o[4] = f2bf(v1.x); o[5] = f2bf(v1.y); o[6] = f2bf(v1.z); o[7] = f2bf(v1.w);
            } else {
#pragma unroll
                for (int j = 0; j < 8; ++j) {
                    int c = ch * 8 + j;
                    o[j] = (c < 500) ? f2bf(src[j]) : (unsigned short)0;
                }
            }
        }
        *(ushort8*)(xb + (size_t)idx * 8) = o;
    } else if (bid < 7744) {
        int idx = (bid - 6464) * 256 + threadIdx.x;
        int k = idx & 511, n = (idx >> 9) & 127, t = idx >> 16;
        float v = (k < 500) ? w_init[((size_t)t * 500 + k) * 128 + n] : 0.f;
        wbt[idx] = f2bf(v);
    } else {
        int rb = bid - 7744;
        const float* arr[10] = {w_pw, w_pw + 16384, w_pw + 2 * 16384,
                                w_pw + 3 * 16384, wq, wk, wv, wo, w1, w2};
        int widx = rb >> 6;
        const float* w = arr[widx];
        int idx = ((rb & 63) << 8) + threadIdx.x;
        int n = idx >> 7, k = idx & 127;
        wt[(size_t)widx * 16384 + idx] = f2bf(w[k * 128 + n]);
    }
}

// ---------------------------------------------------------------------------
// Kernel 1: init conv MFMA, taps fused behind one barrier pair per k0.
// ---------------------------------------------------------------------------
#define TM 80
#define BK 64
__global__ __launch_bounds__(256) void k_initconv_mfma(
        const unsigned short* __restrict__ xb,
        const unsigned short* __restrict__ wbt,
        const float* __restrict__ bias, float* __restrict__ out) {
    __shared__ unsigned short As[84 * BK];        // 10.5 KB (rows l0..l0+83)
    __shared__ unsigned short Ws[5][64 * BK];     // 40 KB  (5 taps x 64n x 64k)
    int tid = threadIdx.x;
    int b = blockIdx.x / 10;
    int rem = blockIdx.x - b * 10;
    int l0 = (rem >> 1) * TM;
    int nh = rem & 1;
    int lane = tid & 63, wave = tid >> 6;
    int kgrp = lane >> 4, lm = lane & 15;

    f32x4 acc[5];
#pragma unroll
    for (int mf = 0; mf < 5; ++mf) acc[mf] = (f32x4)0.f;

    const unsigned short* abase = xb + ((size_t)(b * 404 + l0)) * 512;
    const unsigned short* wbase = wbt + (size_t)nh * 64 * 512;

    for (int k0 = 0; k0 < 512; k0 += BK) {
        for (int idx = tid; idx < 672; idx += 256) {
            int r = idx >> 3, sc = idx & 7;
            gload16(abase + (size_t)r * 512 + k0 + ((sc ^ (r & 7)) * 8),
                    As + idx * 8);
        }
#pragma unroll
        for (int i = 0; i < 10; ++i) {
            int idx = tid + i * 256;
            int t = idx >> 9;          // 0..4
            int sub = idx & 511;
            int n = sub >> 3, sc = sub & 7;
            gload16(wbase + (size_t)t * 128 * 512 + (size_t)n * 512 + k0
                        + ((sc ^ (n & 7)) * 8),
                    &Ws[t][0] + sub * 8);
        }
        __syncthreads();
        int n16 = wave * 16 + lm;
#pragma unroll
        for (int ks = 0; ks < 2; ++ks) {
            int gc = ks * 4 + kgrp;
            bf16x8 bfr[5];
#pragma unroll
            for (int t = 0; t < 5; ++t)
                bfr[t] = *(const bf16x8*)(&Ws[t][0] + n16 * 64
                                          + ((gc ^ (n16 & 7)) * 8));
#pragma unroll
            for (int mf = 0; mf < 5; ++mf) {
#pragma unroll
                for (int t = 0; t < 5; ++t) {
                    int r = mf * 16 + lm + t;
                    bf16x8 af = *(const bf16x8*)(As + r * 64
                                                 + ((gc ^ (r & 7)) * 8));
                    acc[mf] = __builtin_amdgcn_mfma_f32_16x16x32_bf16(
                        af, bfr[t], acc[mf], 0, 0, 0);
                }
            }
        }
        __syncthreads();
    }

    {
        int n = nh * 64 + wave * 16 + lm;
        float bs = bias[n];
        float pbase = expf(-(float)(n & ~1) * (9.210340371976184f / 128.0f));
#pragma unroll
        for (int mf = 0; mf < 5; ++mf) {
#pragma unroll
            for (int r = 0; r < 4; ++r) {
                int l = l0 + mf * 16 + kgrp * 4 + r;
                float ang = (float)l * pbase;
                float pe = (n & 1) ? cosf(ang) : sinf(ang);
                out[((size_t)b * 400 + l) * 128 + n] = acc[mf][r] + bs + pe;
            }
        }
    }
}

// ---------------------------------------------------------------------------
// Kernel 2: fused conv block: pre-LN + depthwise k=7 + pointwise GEMM
// + relu + residual, one HBM round-trip. Grid 832 = 64 b x 13 tiles of 32 l.
// ---------------------------------------------------------------------------
#define CB_ROWS 38
__global__ __launch_bounds__(256) void k_convblock(
        const float* __restrict__ hin, float* __restrict__ hout,
        const float* __restrict__ lng, const float* __restrict__ lnb,
        const float* __restrict__ wdw, const float* __restrict__ bdw,
        const unsigned short* __restrict__ wpt, const float* __restrict__ bpw) {
    __shared__ unsigned short Ws[128 * 128];     // 32 KB pw weight (n-major)
    __shared__ unsigned short Ln[CB_ROWS * 128]; // 9.5 KB LN'd rows (plain)
    __shared__ unsigned short Dw[32 * 128];      // 8 KB dw out (swizzled A)
    int tid = threadIdx.x;
    int b = blockIdx.x / 13;
    int tile = blockIdx.x - b * 13;
    int l0 = tile * 32;
    int lv = (l0 + 32 <= L) ? 32 : (L - l0);
    int lane = tid & 63, wave = tid >> 6;
    int lm = lane & 15, kgrp = lane >> 4;

    // stage pointwise weight early (overlaps LN compute)
#pragma unroll
    for (int i = 0; i < 8; ++i) {
        int idx = tid + i * 256;
        int n = idx >> 4, sc = idx & 15;
        gload16(wpt + (size_t)n * 128 + ((sc ^ (n & 15)) * 8), Ws + idx * 8);
    }

    // LN phase: rows l0-3 .. l0+34, one wave per row (strided by 4)
    {
        float2 gg = *(const float2*)(lng + lane * 2);
        float2 bb = *(const float2*)(lnb + lane * 2);
#pragma unroll
        for (int ri = 0; ri < 10; ++ri) {
            int r = wave + ri * 4;
            if (r < CB_ROWS) {
                int gl = l0 - 3 + r;
                bool ok = (gl >= 0 && gl < L);
                float2 v = make_float2(0.f, 0.f);
                if (ok) v = *(const float2*)(hin + ((size_t)b * L + gl) * 128 + lane * 2);
                float s = v.x + v.y;
                float q = v.x * v.x + v.y * v.y;
#pragma unroll
                for (int off = 32; off; off >>= 1) {
                    s += __shfl_xor(s, off);
                    q += __shfl_xor(q, off);
                }
                float mu  = s * (1.f / 128.f);
                float var = q * (1.f / 128.f) - mu * mu;
                float inv = rsqrtf(var + 1e-5f);
                unsigned pk = 0;
                if (ok) {
                    float ox = (v.x - mu) * inv * gg.x + bb.x;
                    float oy = (v.y - mu) * inv * gg.y + bb.y;
                    pk = (unsigned)f2bf(ox) | ((unsigned)f2bf(oy) << 16);
                }
                *(unsigned*)(Ln + r * 128 + lane * 2) = pk;
            }
        }
    }
    __syncthreads();

    // depthwise conv k=7: thread owns channel d, 16 l rows (rolling window)
    {
        int d = tid & 127, half = tid >> 7;
        float wr[7];
#pragma unroll
        for (int t = 0; t < 7; ++t) wr[t] = wdw[t * 128 + d];
        float bs = bdw[d];
        float win[7];
#pragma unroll
        for (int t = 0; t < 6; ++t) win[t] = bf2f(Ln[(half * 16 + t) * 128 + d]);
#pragma unroll
        for (int lj = 0; lj < 16; ++lj) {
            int l = half * 16 + lj;
            win[6] = bf2f(Ln[(l + 6) * 128 + d]);
            float a = bs;
#pragma unroll
            for (int t = 0; t < 7; ++t) a = fmaf(win[t], wr[t], a);
#pragma unroll
            for (int t = 0; t < 6; ++t) win[t] = win[t + 1];
            Dw[l * 128 + ((d >> 3) ^ (l & 15)) * 8 + (d & 7)] = f2bf(a);
        }
    }
    __syncthreads();

    // pointwise GEMM: [32,128] x [128,128]; wave owns 32-col quarter
    f32x4 acc[2][2];
#pragma unroll
    for (int mf = 0; mf < 2; ++mf)
#pragma unroll
        for (int nt = 0; nt < 2; ++nt) acc[mf][nt] = (f32x4)0.f;
#pragma unroll
    for (int kc = 0; kc < 4; ++kc) {
        int c = kc * 4 + kgrp;
        bf16x8 af[2];
#pragma unroll
        for (int mf = 0; mf < 2; ++mf) {
            int r = mf * 16 + lm;
            af[mf] = *(const bf16x8*)(Dw + r * 128 + (c ^ (r & 15)) * 8);
        }
#pragma unroll
        for (int nt = 0; nt < 2; ++nt) {
            int n = wave * 32 + nt * 16 + lm;
            bf16x8 bfv = *(const bf16x8*)(Ws + n * 128 + (c ^ (n & 15)) * 8);
#pragma unroll
            for (int mf = 0; mf < 2; ++mf)
                acc[mf][nt] = __builtin_amdgcn_mfma_f32_16x16x32_bf16(
                    af[mf], bfv, acc[mf][nt], 0, 0, 0);
        }
    }

    // epilogue: relu(pw + bias) + residual
#pragma unroll
    for (int nt = 0; nt < 2; ++nt) {
        int n = wave * 32 + nt * 16 + lm;
        float bsn = bpw[n];
#pragma unroll
        for (int mf = 0; mf < 2; ++mf) {
#pragma unroll
            for (int r = 0; r < 4; ++r) {
                int row = mf * 16 + kgrp * 4 + r;
                if (row < lv) {
                    size_t gi = ((size_t)b * L + l0 + row) * 128 + n;
                    hout[gi] = fmaxf(acc[mf][nt][r] + bsn, 0.f) + hin[gi];
                }
            }
        }
    }
}

// ---------------------------------------------------------------------------
// Kernel 3: fused LN + GEMM(s). (QKV: nw=3.)
// ---------------------------------------------------------------------------
__global__ __launch_bounds__(256) void k_ln_gemm(
        const float* __restrict__ h, const float* __restrict__ g,
        const float* __restrict__ bta, const unsigned short* __restrict__ wt0,
        int nw, const float* __restrict__ bias0, const float* __restrict__ bias1,
        const float* __restrict__ bias2, unsigned short* __restrict__ out0,
        unsigned short* __restrict__ out1, unsigned short* __restrict__ out2,
        float s0, int relu) {
    __shared__ unsigned short As[32 * 128];   // 8 KB
    __shared__ unsigned short Ws[128 * 128];  // 32 KB
    int tid = threadIdx.x;
    int m0 = blockIdx.x * 32;
    int lane = tid & 63, wave = tid >> 6;
    int lm = lane & 15, kgrp = lane >> 4;
    int wm = wave >> 1, wn = wave & 1;

#pragma unroll
    for (int i = 0; i < 8; ++i) {
        int idx = tid + i * 256;
        int n = idx >> 4, sc = idx & 15;
        gload16(wt0 + (size_t)n * 128 + ((sc ^ (n & 15)) * 8), Ws + idx * 8);
    }

    {
        float2 gg = *(const float2*)(g + lane * 2);
        float2 bb = *(const float2*)(bta + lane * 2);
#pragma unroll
        for (int ri = 0; ri < 8; ++ri) {
            int r = wave + ri * 4;
            float2 v = *(const float2*)(h + ((size_t)m0 + r) * 128 + lane * 2);
            float s = v.x + v.y;
            float q = v.x * v.x + v.y * v.y;
#pragma unroll
            for (int off = 32; off; off >>= 1) {
                s += __shfl_xor(s, off);
                q += __shfl_xor(q, off);
            }
            float mu  = s * (1.f / 128.f);
            float var = q * (1.f / 128.f) - mu * mu;
            float inv = rsqrtf(var + 1e-5f);
            float ox = (v.x - mu) * inv * gg.x + bb.x;
            float oy = (v.y - mu) * inv * gg.y + bb.y;
            unsigned pk = (unsigned)f2bf(ox) | ((unsigned)f2bf(oy) << 16);
            *(unsigned*)(As + r * 128 + ((lane >> 2) ^ (r & 15)) * 8
                         + ((lane * 2) & 7)) = pk;
        }
    }

    for (int i = 0; i < nw; ++i) {
        __syncthreads();
        f32x4 acc[4];
#pragma unroll
        for (int nt = 0; nt < 4; ++nt) acc[nt] = (f32x4)0.f;
#pragma unroll
        for (int kc = 0; kc < 4; ++kc) {
            int c = kc * 4 + kgrp;
            int r = wm * 16 + lm;
            bf16x8 af = *(const bf16x8*)(As + r * 128 + (c ^ (r & 15)) * 8);
#pragma unroll
            for (int nt = 0; nt < 4; ++nt) {
                int n = wn * 64 + nt * 16 + lm;
                bf16x8 bfv = *(const bf16x8*)(Ws + n * 128 + (c ^ (n & 15)) * 8);
                acc[nt] = __builtin_amdgcn_mfma_f32_16x16x32_bf16(
                    af, bfv, acc[nt], 0, 0, 0);
            }
        }
        const float* bias = (i == 0) ? bias0 : (i == 1) ? bias1 : bias2;
        unsigned short* out = (i == 0) ? out0 : (i == 1) ? out1 : out2;
        float sc0 = (i == 0) ? s0 : 1.f;
#pragma unroll
        for (int nt = 0; nt < 4; ++nt) {
            int n = wn * 64 + nt * 16 + lm;
            float bsn = bias[n];
#pragma unroll
            for (int r = 0; r < 4; ++r) {
                size_t m = (size_t)m0 + wm * 16 + kgrp * 4 + r;
                float v = acc[nt][r] + bsn;
                if (relu) v = fmaxf(v, 0.f);
                out[m * 128 + n] = f2bf(v * sc0);
            }
        }
        if (i + 1 < nw) {
            __syncthreads();
            const unsigned short* wp = wt0 + (size_t)(i + 1) * 16384;
#pragma unroll
            for (int j = 0; j < 8; ++j) {
                int idx = tid + j * 256;
                int n = idx >> 4, sc = idx & 15;
                gload16(wp + (size_t)n * 128 + ((sc ^ (n & 15)) * 8), Ws + idx * 8);
            }
        }
    }
}

// ---------------------------------------------------------------------------
// Kernel 4 (new): fused o-proj + residual + FFN (LN -> W1+relu -> W2 + res).
// Per 32-row tile, all within one block (LN needs only the 128-wide row).
// Ws (32 KB) sequentially re-staged wo -> w1 -> w2 behind barriers.
// LDS 64 KB -> 2 blocks/CU. Replaces 3 dispatches / 85 MB with 1 / 33 MB.
// ---------------------------------------------------------------------------
__global__ __launch_bounds__(256) void k_oproj_ffn(
        const unsigned short* __restrict__ A,     // attn out bf16 [BL,128]
        const float* __restrict__ res,            // pre-attn h0 fp32
        const unsigned short* __restrict__ wot, const float* __restrict__ bo,
        const float* __restrict__ lng, const float* __restrict__ lnb,
        const unsigned short* __restrict__ w1t, const float* __restrict__ b1,
        const unsigned short* __restrict__ w2t, const float* __restrict__ b2,
        float* __restrict__ outp) {
    __shared__ unsigned short Ws[128 * 128];   // 32 KB (wo -> w1 -> w2)
    __shared__ unsigned short As[32 * 128];    // 8 KB (attn tile, then LN'd)
    __shared__ float Hm[32 * 128];             // 16 KB h_mid fp32
    __shared__ unsigned short Mid[32 * 128];   // 8 KB ffn mid (A-swizzled)
    int tid = threadIdx.x;
    int m0 = blockIdx.x * 32;
    int lane = tid & 63, wave = tid >> 6;
    int lm = lane & 15, kgrp = lane >> 4;
    int wm = wave >> 1, wn = wave & 1;

    // stage wo^T + attn-out tile
#pragma unroll
    for (int i = 0; i < 8; ++i) {
        int idx = tid + i * 256;
        int n = idx >> 4, sc = idx & 15;
        gload16(wot + (size_t)n * 128 + ((sc ^ (n & 15)) * 8), Ws + idx * 8);
    }
#pragma unroll
    for (int i = 0; i < 2; ++i) {
        int idx = tid + i * 256;
        int r = idx >> 4, sc = idx & 15;
        gload16(A + ((size_t)(m0 + r)) * 128 + ((sc ^ (r & 15)) * 8), As + idx * 8);
    }
    __syncthreads();

    // GEMM1: o-proj; h_mid = acc + bo + res -> Hm (fp32)
    {
        f32x4 acc[4];
#pragma unroll
        for (int nt = 0; nt < 4; ++nt) acc[nt] = (f32x4)0.f;
#pragma unroll
        for (int kc = 0; kc < 4; ++kc) {
            int c = kc * 4 + kgrp;
            int r = wm * 16 + lm;
            bf16x8 af = *(const bf16x8*)(As + (r * 16 + (c ^ (r & 15))) * 8);
#pragma unroll
            for (int nt = 0; nt < 4; ++nt) {
                int n = wn * 64 + nt * 16 + lm;
                bf16x8 bfv = *(const bf16x8*)(Ws + (n * 16 + (c ^ (n & 15))) * 8);
                acc[nt] = __builtin_amdgcn_mfma_f32_16x16x32_bf16(af, bfv, acc[nt], 0, 0, 0);
            }
        }
#pragma unroll
        for (int nt = 0; nt < 4; ++nt) {
            int n = wn * 64 + nt * 16 + lm;
            float bsn = bo[n];
#pragma unroll
            for (int r = 0; r < 4; ++r) {
                int row = wm * 16 + kgrp * 4 + r;
                Hm[row * 128 + n] = acc[nt][r] + bsn
                                    + res[((size_t)m0 + row) * 128 + n];
            }
        }
    }
    __syncthreads();   // all Ws(wo)/As reads + Hm writes done

    // stage w1 (overlaps LN compute)
#pragma unroll
    for (int i = 0; i < 8; ++i) {
        int idx = tid + i * 256;
        int n = idx >> 4, sc = idx & 15;
        gload16(w1t + (size_t)n * 128 + ((sc ^ (n & 15)) * 8), Ws + idx * 8);
    }
    // LN on Hm rows -> As (A-swizzled bf16); same math as k_ln_gemm
    {
        float2 gg = *(const float2*)(lng + lane * 2);
        float2 bb = *(const float2*)(lnb + lane * 2);
#pragma unroll
        for (int ri = 0; ri < 8; ++ri) {
            int r = wave + ri * 4;
            float2 v = *(const float2*)(Hm + r * 128 + lane * 2);
            float s = v.x + v.y;
            float q = v.x * v.x + v.y * v.y;
#pragma unroll
            for (int off = 32; off; off >>= 1) {
                s += __shfl_xor(s, off);
                q += __shfl_xor(q, off);
            }
            float mu  = s * (1.f / 128.f);
            float var = q * (1.f / 128.f) - mu * mu;
            float inv = rsqrtf(var + 1e-5f);
            float ox = (v.x - mu) * inv * gg.x + bb.x;
            float oy = (v.y - mu) * inv * gg.y + bb.y;
            unsigned pk = (unsigned)f2bf(ox) | ((unsigned)f2bf(oy) << 16);
            *(unsigned*)(As + r * 128 + ((lane >> 2) ^ (r & 15)) * 8
                         + ((lane * 2) & 7)) = pk;
        }
    }
    __syncthreads();   // Ws(w1) staged, As(LN) written

    // GEMM2: x W1 + b1, relu -> Mid (A-swizzled bf16)
    {
        f32x4 acc[4];
#pragma unroll
        for (int nt = 0; nt < 4; ++nt) acc[nt] = (f32x4)0.f;
#pragma unroll
        for (int kc = 0; kc < 4; ++kc) {
            int c = kc * 4 + kgrp;
            int r = wm * 16 + lm;
            bf16x8 af = *(const bf16x8*)(As + (r * 16 + (c ^ (r & 15))) * 8);
#pragma unroll
            for (int nt = 0; nt < 4; ++nt) {
                int n = wn * 64 + nt * 16 + lm;
                bf16x8 bfv = *(const bf16x8*)(Ws + (n * 16 + (c ^ (n & 15))) * 8);
                acc[nt] = __builtin_amdgcn_mfma_f32_16x16x32_bf16(af, bfv, acc[nt], 0, 0, 0);
            }
        }
#pragma unroll
        for (int nt = 0; nt < 4; ++nt) {
            int n = wn * 64 + nt * 16 + lm;
            float bsn = b1[n];
#pragma unroll
            for (int r = 0; r < 4; ++r) {
                int row = wm * 16 + kgrp * 4 + r;
                float v = fmaxf(acc[nt][r] + bsn, 0.f);
                Mid[row * 128 + ((n >> 3) ^ (row & 15)) * 8 + (n & 7)] = f2bf(v);
            }
        }
    }
    __syncthreads();   // all Ws(w1) reads + Mid writes done

    // stage w2
#pragma unroll
    for (int i = 0; i < 8; ++i) {
        int idx = tid + i * 256;
        int n = idx >> 4, sc = idx & 15;
        gload16(w2t + (size_t)n * 128 + ((sc ^ (n & 15)) * 8), Ws + idx * 8);
    }
    __syncthreads();   // Ws(w2) staged

    // GEMM3: x W2 + b2 + Hm -> outp
    {
        f32x4 acc[4];
#pragma unroll
        for (int nt = 0; nt < 4; ++nt) acc[nt] = (f32x4)0.f;
#pragma unroll
        for (int kc = 0; kc < 4; ++kc) {
            int c = kc * 4 + kgrp;
            int r = wm * 16 + lm;
            bf16x8 af = *(const bf16x8*)(Mid + (r * 16 + (c ^ (r & 15))) * 8);
#pragma unroll
            for (int nt = 0; nt < 4; ++nt) {
                int n = wn * 64 + nt * 16 + lm;
                bf16x8 bfv = *(const bf16x8*)(Ws + (n * 16 + (c ^ (n & 15))) * 8);
                acc[nt] = __builtin_amdgcn_mfma_f32_16x16x32_bf16(af, bfv, acc[nt], 0, 0, 0);
            }
        }
#pragma unroll
        for (int nt = 0; nt < 4; ++nt) {
            int n = wn * 64 + nt * 16 + lm;
            float bsn = b2[n];
#pragma unroll
            for (int r = 0; r < 4; ++r) {
                int row = wm * 16 + kgrp * 4 + r;
                outp[((size_t)m0 + row) * 128 + n] =
                    acc[nt][r] + bsn + Hm[row * 128 + n];
            }
        }
    }
}

// ---------------------------------------------------------------------------
// Kernel 5: swapped QK^T + LDS P-bounce (R9-verified, absmax 0.03125).
// ---------------------------------------------------------------------------
#define KS 40
#define VS 424
__global__ __launch_bounds__(512) void k_attn_mfma(
        const unsigned short* __restrict__ qb,
        const unsigned short* __restrict__ kb,
        const unsigned short* __restrict__ vb,
        unsigned short* __restrict__ out) {
    __shared__ __align__(16) unsigned short Kpad[400 * KS];
    __shared__ __align__(16) unsigned short Vt[16 * VS];
    __shared__ __align__(16) unsigned short Ptmp[8][16 * KS];
    int tid = threadIdx.x;
    int b = blockIdx.x & 63, h = blockIdx.x >> 6;   // XCD-grouping swizzle
    int lane = tid & 63, wave = tid >> 6;
    int lm = lane & 15, g = lane >> 4;

    for (int idx = tid; idx < 800; idx += 512) {
        int l = idx >> 1, half = idx & 1;
        ushort8 kv = *(const ushort8*)(kb + ((size_t)(b * 400 + l)) * 128 + h * 16 + half * 8);
        *(ushort8*)(Kpad + l * KS + half * 8) = kv;
        *(ushort8*)(Kpad + l * KS + 16 + half * 8) = (ushort8)0;
    }
    for (int idx = tid; idx < 800; idx += 512) {
        int kk = idx >> 1, dh = idx & 1;
        ushort8 vv = *(const ushort8*)(vb + ((size_t)(b * 400 + kk)) * 128 + h * 16 + dh * 8);
#pragma unroll
        for (int j = 0; j < 8; ++j) Vt[(dh * 8 + j) * VS + kk] = vv[j];
    }
    if (tid < 256) {
        int d = tid >> 4, kk = 400 + (tid & 15);
        Vt[d * VS + kk] = 0;
    }
    __syncthreads();

    unsigned short* Pw = Ptmp[wave];
    for (int tt = wave; tt < 25; tt += 8) {
        int q0 = tt * 16;
        bf16x8 Qf = *(const bf16x8*)(qb + ((size_t)(b * 400 + q0 + lm)) * 128 + h * 16 + g * 8);
        f32x4 s[25];
        __builtin_amdgcn_s_setprio(1);
#pragma unroll
        for (int kt = 0; kt < 25; ++kt) {
            bf16x8 Kf = *(const bf16x8*)(Kpad + (kt * 16 + lm) * KS + g * 8);
            s[kt] = __builtin_amdgcn_mfma_f32_16x16x32_bf16(Kf, Qf, (f32x4)0.f, 0, 0, 0);
        }
        __builtin_amdgcn_s_setprio(0);
        float m = -1e30f;
#pragma unroll
        for (int kt = 0; kt < 25; ++kt)
            m = fmaxf(m, fmaxf(fmaxf(s[kt][0], s[kt][1]),
                               fmaxf(s[kt][2], s[kt][3])));
        m = fmaxf(m, __shfl_xor(m, 16));
        m = fmaxf(m, __shfl_xor(m, 32));

        f32x4 O = (f32x4)0.f;
        f32x4 sumv = (f32x4)0.f;
#pragma unroll
        for (int kc = 0; kc < 13; ++kc) {
            {
                int kt = 2 * kc;
                f32x4 p;
                p[0] = __expf(s[kt][0] - m);
                p[1] = __expf(s[kt][1] - m);
                p[2] = __expf(s[kt][2] - m);
                p[3] = __expf(s[kt][3] - m);
                sumv += p;
                uint2 w; w.x = cvtpk_bf16(p[0], p[1]); w.y = cvtpk_bf16(p[2], p[3]);
                *(uint2*)(Pw + lm * KS + g * 4) = w;
            }
            {
                int kt = 2 * kc + 1;
                uint2 w; w.x = 0u; w.y = 0u;
                if (kt < 25) {
                    f32x4 p;
                    p[0] = __expf(s[kt][0] - m);
                    p[1] = __expf(s[kt][1] - m);
                    p[2] = __expf(s[kt][2] - m);
                    p[3] = __expf(s[kt][3] - m);
                    sumv += p;
                    w.x = cvtpk_bf16(p[0], p[1]); w.y = cvtpk_bf16(p[2], p[3]);
                }
                *(uint2*)(Pw + lm * KS + 16 + g * 4) = w;
            }
            __builtin_amdgcn_wave_barrier();
            asm volatile("s_waitcnt lgkmcnt(0)" ::: "memory");
            __builtin_amdgcn_sched_barrier(0);
            bf16x8 Pf = *(const bf16x8*)(Pw + lm * KS + g * 8);
            bf16x8 Vf = *(const bf16x8*)(Vt + lm * VS + kc * 32 + g * 8);
            O = __builtin_amdgcn_mfma_f32_16x16x32_bf16(Pf, Vf, O, 0, 0, 0);
            __builtin_amdgcn_wave_barrier();
        }
        float sum = (sumv[0] + sumv[1]) + (sumv[2] + sumv[3]);
        sum += __shfl_xor(sum, 16);
        sum += __shfl_xor(sum, 32);
        float rinv = 1.f / sum;
#pragma unroll
        for (int r = 0; r < 4; ++r) {
            float rq = __shfl(rinv, g * 4 + r);
            int q = q0 + g * 4 + r;
            out[((size_t)(b * 400 + q)) * 128 + h * 16 + lm] = f2bf(O[r] * rq);
        }
    }
}

// ---------------------------------------------------------------------------
extern "C" void kernel_launch(void* const* d_in, const int* in_sizes, int n_in,
                              void* d_out, int out_size, void* d_ws, size_t ws_size,
                              hipStream_t stream) {
    (void)in_sizes; (void)n_in; (void)out_size; (void)ws_size;
    const float* x      = (const float*)d_in[0];
    const float* w_init = (const float*)d_in[1];
    const float* b_init = (const float*)d_in[2];
    const float* lncg   = (const float*)d_in[3];
    const float* lncb   = (const float*)d_in[4];
    const float* w_dw   = (const float*)d_in[5];
    const float* b_dw   = (const float*)d_in[6];
    const float* w_pw   = (const float*)d_in[7];
    const float* b_pw   = (const float*)d_in[8];
    const float* lnag   = (const float*)d_in[9];
    const float* lnab   = (const float*)d_in[10];
    const float* wq     = (const float*)d_in[11];
    const float* bq     = (const float*)d_in[12];
    const float* wk     = (const float*)d_in[13];
    const float* bk     = (const float*)d_in[14];
    const float* wv     = (const float*)d_in[15];
    const float* bv     = (const float*)d_in[16];
    const float* wo     = (const float*)d_in[17];
    const float* bo     = (const float*)d_in[18];
    const float* lnfg   = (const float*)d_in[19];
    const float* lnfb   = (const float*)d_in[20];
    const float* w1     = (const float*)d_in[21];
    const float* b1     = (const float*)d_in[22];
    const float* w2     = (const float*)d_in[23];
    const float* b2     = (const float*)d_in[24];

    float* ws = (float*)d_ws;
    const size_t NBL = (size_t)BL * D;
    float* h0 = ws;
    float* outp = (float*)d_out;

    unsigned short* hnb = (unsigned short*)(ws + NBL);
    unsigned short* t0b = hnb + NBL;
    unsigned short* qb  = t0b + NBL;
    unsigned short* kb  = qb + NBL;
    unsigned short* vb  = kb + NBL;
    unsigned short* wt  = vb + NBL;
    unsigned short* xb  = wt + 10 * 16384;
    unsigned short* wbt = xb + (size_t)64 * 404 * 512;
    float* h1 = (float*)(wbt + (size_t)5 * 128 * 512);   // ping-pong buffer

    // merged pre-pass (x cvt + w_init cvt + 10x weight transpose)
    k_cvt_all<<<8384, 256, 0, stream>>>(x, xb, w_init, wbt,
                                        w_pw, wq, wk, wv, wo, w1, w2, wt);

    // 1) init conv + posenc
    k_initconv_mfma<<<640, 256, 0, stream>>>(xb, wbt, b_init, h0);

    // 2) 4x fused conv blocks, ping-pong h0 <-> h1
    for (int i = 0; i < NCONV; ++i) {
        const float* hin = (i & 1) ? h1 : h0;
        float* hout      = (i & 1) ? h0 : h1;
        k_convblock<<<832, 256, 0, stream>>>(
            hin, hout, lncg + i * D, lncb + i * D,
            w_dw + (size_t)i * 7 * D, b_dw + i * D,
            wt + (size_t)i * 16384, b_pw + i * D);
    }

    // 3) attention: fused LN + QKV (one A-stage, three weights)
    k_ln_gemm<<<800, 256, 0, stream>>>(h0, lnag, lnab, wt + 4 * 16384, 3,
                                       bq, bk, bv, qb, kb, vb, 0.25f, 0);
    k_attn_mfma<<<512, 512, 0, stream>>>(qb, kb, vb, t0b);

    // 4) fused o-proj + residual + FFN -> out
    k_oproj_ffn<<<800, 256, 0, stream>>>(
        t0b, h0, wt + 7 * 16384, bo, lnfg, lnfb,
        wt + 8 * 16384, b1, wt + 9 * 16384, b2, outp);
}

// Round 11
// 305.182 us; speedup vs baseline: 1.0544x; 1.0094x over previous
//
#include <hip/hip_runtime.h>
#include <hip/hip_bf16.h>
#include <math.h>

#define B 64
#define L 400
#define IN_DIM 500
#define D 128
#define H 8
#define HD 16
#define NCONV 4
#define BL (B*L)

typedef __attribute__((ext_vector_type(8))) unsigned short ushort8;
typedef __attribute__((ext_vector_type(8))) short bf16x8;
typedef __attribute__((ext_vector_type(4))) float f32x4;

__device__ __forceinline__ unsigned short f2bf(float f) {
    unsigned u = __float_as_uint(f);
    unsigned r = (u + 0x7fffu + ((u >> 16) & 1u)) >> 16;
    return (unsigned short)r;
}
__device__ __forceinline__ float bf2f(unsigned short u) {
    return __uint_as_float(((unsigned)u) << 16);
}
__device__ __forceinline__ unsigned cvtpk_bf16(float lo, float hi) {
    unsigned r;
    asm("v_cvt_pk_bf16_f32 %0, %1, %2" : "=v"(r) : "v"(lo), "v"(hi));
    return r;
}

__device__ __forceinline__ void gload16(const void* g, void* l) {
    __builtin_amdgcn_global_load_lds(
        (const __attribute__((address_space(1))) unsigned int*)g,
        (__attribute__((address_space(3))) unsigned int*)l,
        16, 0, 0);
}

// ---------------------------------------------------------------------------
// Merged pre-pass: [0,6464) cvt_x; [6464,7744) cvt_w; [7744,8384) cvt_wall.
// ---------------------------------------------------------------------------
__global__ __launch_bounds__(256) void k_cvt_all(
        const float* __restrict__ x, unsigned short* __restrict__ xb,
        const float* __restrict__ w_init, unsigned short* __restrict__ wbt,
        const float* __restrict__ w_pw, const float* __restrict__ wq,
        const float* __restrict__ wk, const float* __restrict__ wv,
        const float* __restrict__ wo, const float* __restrict__ w1,
        const float* __restrict__ w2, unsigned short* __restrict__ wt) {
    int bid = blockIdx.x;
    if (bid < 6464) {
        int idx = bid * 256 + threadIdx.x;   // chunk of 8 bf16
        int row = idx >> 6, ch = idx & 63;
        int b = row / 404, rr = row - b * 404;
        ushort8 o = (ushort8)0;
        if (rr >= 2 && rr < 402) {
            int l = rr - 2;
            const float* src = x + ((size_t)b * 400 + l) * 500 + ch * 8;
            if (ch < 62) {
                float4 v0 = *(const float4*)(src);
                float4 v1 = *(const float4*)(src + 4);
                o[0] = f2bf(v0.x); o[1] = f2bf(v0.y); o[2] = f2bf(v0.z); o[3] = f2bf(v0.w);
                o[4] = f2bf(v1.x); o[5] = f2bf(v1.y); o[6] = f2bf(v1.z); o[7] = f2bf(v1.w);
            } else {
#pragma unroll
                for (int j = 0; j < 8; ++j) {
                    int c = ch * 8 + j;
                    o[j] = (c < 500) ? f2bf(src[j]) : (unsigned short)0;
                }
            }
        }
        *(ushort8*)(xb + (size_t)idx * 8) = o;
    } else if (bid < 7744) {
        int idx = (bid - 6464) * 256 + threadIdx.x;
        int k = idx & 511, n = (idx >> 9) & 127, t = idx >> 16;
        float v = (k < 500) ? w_init[((size_t)t * 500 + k) * 128 + n] : 0.f;
        wbt[idx] = f2bf(v);
    } else {
        int rb = bid - 7744;
        const float* arr[10] = {w_pw, w_pw + 16384, w_pw + 2 * 16384,
                                w_pw + 3 * 16384, wq, wk, wv, wo, w1, w2};
        int widx = rb >> 6;
        const float* w = arr[widx];
        int idx = ((rb & 63) << 8) + threadIdx.x;
        int n = idx >> 7, k = idx & 127;
        wt[(size_t)widx * 16384 + idx] = f2bf(w[k * 128 + n]);
    }
}

// ---------------------------------------------------------------------------
// Kernel 1: init conv MFMA, taps fused behind one barrier pair per k0.
// ---------------------------------------------------------------------------
#define TM 80
#define BK 64
__global__ __launch_bounds__(256) void k_initconv_mfma(
        const unsigned short* __restrict__ xb,
        const unsigned short* __restrict__ wbt,
        const float* __restrict__ bias, float* __restrict__ out) {
    __shared__ unsigned short As[84 * BK];        // 10.5 KB (rows l0..l0+83)
    __shared__ unsigned short Ws[5][64 * BK];     // 40 KB  (5 taps x 64n x 64k)
    int tid = threadIdx.x;
    int b = blockIdx.x / 10;
    int rem = blockIdx.x - b * 10;
    int l0 = (rem >> 1) * TM;
    int nh = rem & 1;
    int lane = tid & 63, wave = tid >> 6;
    int kgrp = lane >> 4, lm = lane & 15;

    f32x4 acc[5];
#pragma unroll
    for (int mf = 0; mf < 5; ++mf) acc[mf] = (f32x4)0.f;

    const unsigned short* abase = xb + ((size_t)(b * 404 + l0)) * 512;
    const unsigned short* wbase = wbt + (size_t)nh * 64 * 512;

    for (int k0 = 0; k0 < 512; k0 += BK) {
        for (int idx = tid; idx < 672; idx += 256) {
            int r = idx >> 3, sc = idx & 7;
            gload16(abase + (size_t)r * 512 + k0 + ((sc ^ (r & 7)) * 8),
                    As + idx * 8);
        }
#pragma unroll
        for (int i = 0; i < 10; ++i) {
            int idx = tid + i * 256;
            int t = idx >> 9;          // 0..4
            int sub = idx & 511;
            int n = sub >> 3, sc = sub & 7;
            gload16(wbase + (size_t)t * 128 * 512 + (size_t)n * 512 + k0
                        + ((sc ^ (n & 7)) * 8),
                    &Ws[t][0] + sub * 8);
        }
        __syncthreads();
        int n16 = wave * 16 + lm;
#pragma unroll
        for (int ks = 0; ks < 2; ++ks) {
            int gc = ks * 4 + kgrp;
            bf16x8 bfr[5];
#pragma unroll
            for (int t = 0; t < 5; ++t)
                bfr[t] = *(const bf16x8*)(&Ws[t][0] + n16 * 64
                                          + ((gc ^ (n16 & 7)) * 8));
#pragma unroll
            for (int mf = 0; mf < 5; ++mf) {
#pragma unroll
                for (int t = 0; t < 5; ++t) {
                    int r = mf * 16 + lm + t;
                    bf16x8 af = *(const bf16x8*)(As + r * 64
                                                 + ((gc ^ (r & 7)) * 8));
                    acc[mf] = __builtin_amdgcn_mfma_f32_16x16x32_bf16(
                        af, bfr[t], acc[mf], 0, 0, 0);
                }
            }
        }
        __syncthreads();
    }

    {
        int n = nh * 64 + wave * 16 + lm;
        float bs = bias[n];
        float pbase = expf(-(float)(n & ~1) * (9.210340371976184f / 128.0f));
#pragma unroll
        for (int mf = 0; mf < 5; ++mf) {
#pragma unroll
            for (int r = 0; r < 4; ++r) {
                int l = l0 + mf * 16 + kgrp * 4 + r;
                float ang = (float)l * pbase;
                float pe = (n & 1) ? cosf(ang) : sinf(ang);
                out[((size_t)b * 400 + l) * 128 + n] = acc[mf][r] + bs + pe;
            }
        }
    }
}

// ---------------------------------------------------------------------------
// Kernel 2: fused conv block: pre-LN + depthwise k=7 + pointwise GEMM
// + relu + residual, one HBM round-trip. Grid 832 = 64 b x 13 tiles of 32 l.
// ---------------------------------------------------------------------------
#define CB_ROWS 38
__global__ __launch_bounds__(256) void k_convblock(
        const float* __restrict__ hin, float* __restrict__ hout,
        const float* __restrict__ lng, const float* __restrict__ lnb,
        const float* __restrict__ wdw, const float* __restrict__ bdw,
        const unsigned short* __restrict__ wpt, const float* __restrict__ bpw) {
    __shared__ unsigned short Ws[128 * 128];     // 32 KB pw weight (n-major)
    __shared__ unsigned short Ln[CB_ROWS * 128]; // 9.5 KB LN'd rows (plain)
    __shared__ unsigned short Dw[32 * 128];      // 8 KB dw out (swizzled A)
    int tid = threadIdx.x;
    int b = blockIdx.x / 13;
    int tile = blockIdx.x - b * 13;
    int l0 = tile * 32;
    int lv = (l0 + 32 <= L) ? 32 : (L - l0);
    int lane = tid & 63, wave = tid >> 6;
    int lm = lane & 15, kgrp = lane >> 4;

    // stage pointwise weight early (overlaps LN compute)
#pragma unroll
    for (int i = 0; i < 8; ++i) {
        int idx = tid + i * 256;
        int n = idx >> 4, sc = idx & 15;
        gload16(wpt + (size_t)n * 128 + ((sc ^ (n & 15)) * 8), Ws + idx * 8);
    }

    // LN phase: rows l0-3 .. l0+34, one wave per row (strided by 4)
    {
        float2 gg = *(const float2*)(lng + lane * 2);
        float2 bb = *(const float2*)(lnb + lane * 2);
#pragma unroll
        for (int ri = 0; ri < 10; ++ri) {
            int r = wave + ri * 4;
            if (r < CB_ROWS) {
                int gl = l0 - 3 + r;
                bool ok = (gl >= 0 && gl < L);
                float2 v = make_float2(0.f, 0.f);
                if (ok) v = *(const float2*)(hin + ((size_t)b * L + gl) * 128 + lane * 2);
                float s = v.x + v.y;
                float q = v.x * v.x + v.y * v.y;
#pragma unroll
                for (int off = 32; off; off >>= 1) {
                    s += __shfl_xor(s, off);
                    q += __shfl_xor(q, off);
                }
                float mu  = s * (1.f / 128.f);
                float var = q * (1.f / 128.f) - mu * mu;
                float inv = rsqrtf(var + 1e-5f);
                unsigned pk = 0;
                if (ok) {
                    float ox = (v.x - mu) * inv * gg.x + bb.x;
                    float oy = (v.y - mu) * inv * gg.y + bb.y;
                    pk = (unsigned)f2bf(ox) | ((unsigned)f2bf(oy) << 16);
                }
                *(unsigned*)(Ln + r * 128 + lane * 2) = pk;
            }
        }
    }
    __syncthreads();

    // depthwise conv k=7: thread owns channel d, 16 l rows (rolling window)
    {
        int d = tid & 127, half = tid >> 7;
        float wr[7];
#pragma unroll
        for (int t = 0; t < 7; ++t) wr[t] = wdw[t * 128 + d];
        float bs = bdw[d];
        float win[7];
#pragma unroll
        for (int t = 0; t < 6; ++t) win[t] = bf2f(Ln[(half * 16 + t) * 128 + d]);
#pragma unroll
        for (int lj = 0; lj < 16; ++lj) {
            int l = half * 16 + lj;
            win[6] = bf2f(Ln[(l + 6) * 128 + d]);
            float a = bs;
#pragma unroll
            for (int t = 0; t < 7; ++t) a = fmaf(win[t], wr[t], a);
#pragma unroll
            for (int t = 0; t < 6; ++t) win[t] = win[t + 1];
            Dw[l * 128 + ((d >> 3) ^ (l & 15)) * 8 + (d & 7)] = f2bf(a);
        }
    }
    __syncthreads();

    // pointwise GEMM: [32,128] x [128,128]; wave owns 32-col quarter
    f32x4 acc[2][2];
#pragma unroll
    for (int mf = 0; mf < 2; ++mf)
#pragma unroll
        for (int nt = 0; nt < 2; ++nt) acc[mf][nt] = (f32x4)0.f;
#pragma unroll
    for (int kc = 0; kc < 4; ++kc) {
        int c = kc * 4 + kgrp;
        bf16x8 af[2];
#pragma unroll
        for (int mf = 0; mf < 2; ++mf) {
            int r = mf * 16 + lm;
            af[mf] = *(const bf16x8*)(Dw + r * 128 + (c ^ (r & 15)) * 8);
        }
#pragma unroll
        for (int nt = 0; nt < 2; ++nt) {
            int n = wave * 32 + nt * 16 + lm;
            bf16x8 bfv = *(const bf16x8*)(Ws + n * 128 + (c ^ (n & 15)) * 8);
#pragma unroll
            for (int mf = 0; mf < 2; ++mf)
                acc[mf][nt] = __builtin_amdgcn_mfma_f32_16x16x32_bf16(
                    af[mf], bfv, acc[mf][nt], 0, 0, 0);
        }
    }

    // epilogue: relu(pw + bias) + residual
#pragma unroll
    for (int nt = 0; nt < 2; ++nt) {
        int n = wave * 32 + nt * 16 + lm;
        float bsn = bpw[n];
#pragma unroll
        for (int mf = 0; mf < 2; ++mf) {
#pragma unroll
            for (int r = 0; r < 4; ++r) {
                int row = mf * 16 + kgrp * 4 + r;
                if (row < lv) {
                    size_t gi = ((size_t)b * L + l0 + row) * 128 + n;
                    hout[gi] = fmaxf(acc[mf][nt][r] + bsn, 0.f) + hin[gi];
                }
            }
        }
    }
}

// ---------------------------------------------------------------------------
// Kernel 3: fused LN + GEMM(s). (QKV: nw=3.)
// ---------------------------------------------------------------------------
__global__ __launch_bounds__(256) void k_ln_gemm(
        const float* __restrict__ h, const float* __restrict__ g,
        const float* __restrict__ bta, const unsigned short* __restrict__ wt0,
        int nw, const float* __restrict__ bias0, const float* __restrict__ bias1,
        const float* __restrict__ bias2, unsigned short* __restrict__ out0,
        unsigned short* __restrict__ out1, unsigned short* __restrict__ out2,
        float s0, int relu) {
    __shared__ unsigned short As[32 * 128];   // 8 KB
    __shared__ unsigned short Ws[128 * 128];  // 32 KB
    int tid = threadIdx.x;
    int m0 = blockIdx.x * 32;
    int lane = tid & 63, wave = tid >> 6;
    int lm = lane & 15, kgrp = lane >> 4;
    int wm = wave >> 1, wn = wave & 1;

#pragma unroll
    for (int i = 0; i < 8; ++i) {
        int idx = tid + i * 256;
        int n = idx >> 4, sc = idx & 15;
        gload16(wt0 + (size_t)n * 128 + ((sc ^ (n & 15)) * 8), Ws + idx * 8);
    }

    {
        float2 gg = *(const float2*)(g + lane * 2);
        float2 bb = *(const float2*)(bta + lane * 2);
#pragma unroll
        for (int ri = 0; ri < 8; ++ri) {
            int r = wave + ri * 4;
            float2 v = *(const float2*)(h + ((size_t)m0 + r) * 128 + lane * 2);
            float s = v.x + v.y;
            float q = v.x * v.x + v.y * v.y;
#pragma unroll
            for (int off = 32; off; off >>= 1) {
                s += __shfl_xor(s, off);
                q += __shfl_xor(q, off);
            }
            float mu  = s * (1.f / 128.f);
            float var = q * (1.f / 128.f) - mu * mu;
            float inv = rsqrtf(var + 1e-5f);
            float ox = (v.x - mu) * inv * gg.x + bb.x;
            float oy = (v.y - mu) * inv * gg.y + bb.y;
            unsigned pk = (unsigned)f2bf(ox) | ((unsigned)f2bf(oy) << 16);
            *(unsigned*)(As + r * 128 + ((lane >> 2) ^ (r & 15)) * 8
                         + ((lane * 2) & 7)) = pk;
        }
    }

    for (int i = 0; i < nw; ++i) {
        __syncthreads();
        f32x4 acc[4];
#pragma unroll
        for (int nt = 0; nt < 4; ++nt) acc[nt] = (f32x4)0.f;
#pragma unroll
        for (int kc = 0; kc < 4; ++kc) {
            int c = kc * 4 + kgrp;
            int r = wm * 16 + lm;
            bf16x8 af = *(const bf16x8*)(As + r * 128 + (c ^ (r & 15)) * 8);
#pragma unroll
            for (int nt = 0; nt < 4; ++nt) {
                int n = wn * 64 + nt * 16 + lm;
                bf16x8 bfv = *(const bf16x8*)(Ws + n * 128 + (c ^ (n & 15)) * 8);
                acc[nt] = __builtin_amdgcn_mfma_f32_16x16x32_bf16(
                    af, bfv, acc[nt], 0, 0, 0);
            }
        }
        const float* bias = (i == 0) ? bias0 : (i == 1) ? bias1 : bias2;
        unsigned short* out = (i == 0) ? out0 : (i == 1) ? out1 : out2;
        float sc0 = (i == 0) ? s0 : 1.f;
#pragma unroll
        for (int nt = 0; nt < 4; ++nt) {
            int n = wn * 64 + nt * 16 + lm;
            float bsn = bias[n];
#pragma unroll
            for (int r = 0; r < 4; ++r) {
                size_t m = (size_t)m0 + wm * 16 + kgrp * 4 + r;
                float v = acc[nt][r] + bsn;
                if (relu) v = fmaxf(v, 0.f);
                out[m * 128 + n] = f2bf(v * sc0);
            }
        }
        if (i + 1 < nw) {
            __syncthreads();
            const unsigned short* wp = wt0 + (size_t)(i + 1) * 16384;
#pragma unroll
            for (int j = 0; j < 8; ++j) {
                int idx = tid + j * 256;
                int n = idx >> 4, sc = idx & 15;
                gload16(wp + (size_t)n * 128 + ((sc ^ (n & 15)) * 8), Ws + idx * 8);
            }
        }
    }
}

// ---------------------------------------------------------------------------
// Kernel 4: fused o-proj + residual + FFN (LN -> W1+relu -> W2 + res).
// ---------------------------------------------------------------------------
__global__ __launch_bounds__(256) void k_oproj_ffn(
        const unsigned short* __restrict__ A,     // attn out bf16 [BL,128]
        const float* __restrict__ res,            // pre-attn h0 fp32
        const unsigned short* __restrict__ wot, const float* __restrict__ bo,
        const float* __restrict__ lng, const float* __restrict__ lnb,
        const unsigned short* __restrict__ w1t, const float* __restrict__ b1,
        const unsigned short* __restrict__ w2t, const float* __restrict__ b2,
        float* __restrict__ outp) {
    __shared__ unsigned short Ws[128 * 128];   // 32 KB (wo -> w1 -> w2)
    __shared__ unsigned short As[32 * 128];    // 8 KB (attn tile, then LN'd)
    __shared__ float Hm[32 * 128];             // 16 KB h_mid fp32
    __shared__ unsigned short Mid[32 * 128];   // 8 KB ffn mid (A-swizzled)
    int tid = threadIdx.x;
    int m0 = blockIdx.x * 32;
    int lane = tid & 63, wave = tid >> 6;
    int lm = lane & 15, kgrp = lane >> 4;
    int wm = wave >> 1, wn = wave & 1;

    // stage wo^T + attn-out tile
#pragma unroll
    for (int i = 0; i < 8; ++i) {
        int idx = tid + i * 256;
        int n = idx >> 4, sc = idx & 15;
        gload16(wot + (size_t)n * 128 + ((sc ^ (n & 15)) * 8), Ws + idx * 8);
    }
#pragma unroll
    for (int i = 0; i < 2; ++i) {
        int idx = tid + i * 256;
        int r = idx >> 4, sc = idx & 15;
        gload16(A + ((size_t)(m0 + r)) * 128 + ((sc ^ (r & 15)) * 8), As + idx * 8);
    }
    __syncthreads();

    // GEMM1: o-proj; h_mid = acc + bo + res -> Hm (fp32)
    {
        f32x4 acc[4];
#pragma unroll
        for (int nt = 0; nt < 4; ++nt) acc[nt] = (f32x4)0.f;
#pragma unroll
        for (int kc = 0; kc < 4; ++kc) {
            int c = kc * 4 + kgrp;
            int r = wm * 16 + lm;
            bf16x8 af = *(const bf16x8*)(As + (r * 16 + (c ^ (r & 15))) * 8);
#pragma unroll
            for (int nt = 0; nt < 4; ++nt) {
                int n = wn * 64 + nt * 16 + lm;
                bf16x8 bfv = *(const bf16x8*)(Ws + (n * 16 + (c ^ (n & 15))) * 8);
                acc[nt] = __builtin_amdgcn_mfma_f32_16x16x32_bf16(af, bfv, acc[nt], 0, 0, 0);
            }
        }
#pragma unroll
        for (int nt = 0; nt < 4; ++nt) {
            int n = wn * 64 + nt * 16 + lm;
            float bsn = bo[n];
#pragma unroll
            for (int r = 0; r < 4; ++r) {
                int row = wm * 16 + kgrp * 4 + r;
                Hm[row * 128 + n] = acc[nt][r] + bsn
                                    + res[((size_t)m0 + row) * 128 + n];
            }
        }
    }
    __syncthreads();   // all Ws(wo)/As reads + Hm writes done

    // stage w1 (overlaps LN compute)
#pragma unroll
    for (int i = 0; i < 8; ++i) {
        int idx = tid + i * 256;
        int n = idx >> 4, sc = idx & 15;
        gload16(w1t + (size_t)n * 128 + ((sc ^ (n & 15)) * 8), Ws + idx * 8);
    }
    // LN on Hm rows -> As (A-swizzled bf16); same math as k_ln_gemm
    {
        float2 gg = *(const float2*)(lng + lane * 2);
        float2 bb = *(const float2*)(lnb + lane * 2);
#pragma unroll
        for (int ri = 0; ri < 8; ++ri) {
            int r = wave + ri * 4;
            float2 v = *(const float2*)(Hm + r * 128 + lane * 2);
            float s = v.x + v.y;
            float q = v.x * v.x + v.y * v.y;
#pragma unroll
            for (int off = 32; off; off >>= 1) {
                s += __shfl_xor(s, off);
                q += __shfl_xor(q, off);
            }
            float mu  = s * (1.f / 128.f);
            float var = q * (1.f / 128.f) - mu * mu;
            float inv = rsqrtf(var + 1e-5f);
            float ox = (v.x - mu) * inv * gg.x + bb.x;
            float oy = (v.y - mu) * inv * gg.y + bb.y;
            unsigned pk = (unsigned)f2bf(ox) | ((unsigned)f2bf(oy) << 16);
            *(unsigned*)(As + r * 128 + ((lane >> 2) ^ (r & 15)) * 8
                         + ((lane * 2) & 7)) = pk;
        }
    }
    __syncthreads();   // Ws(w1) staged, As(LN) written

    // GEMM2: x W1 + b1, relu -> Mid (A-swizzled bf16)
    {
        f32x4 acc[4];
#pragma unroll
        for (int nt = 0; nt < 4; ++nt) acc[nt] = (f32x4)0.f;
#pragma unroll
        for (int kc = 0; kc < 4; ++kc) {
            int c = kc * 4 + kgrp;
            int r = wm * 16 + lm;
            bf16x8 af = *(const bf16x8*)(As + (r * 16 + (c ^ (r & 15))) * 8);
#pragma unroll
            for (int nt = 0; nt < 4; ++nt) {
                int n = wn * 64 + nt * 16 + lm;
                bf16x8 bfv = *(const bf16x8*)(Ws + (n * 16 + (c ^ (n & 15))) * 8);
                acc[nt] = __builtin_amdgcn_mfma_f32_16x16x32_bf16(af, bfv, acc[nt], 0, 0, 0);
            }
        }
#pragma unroll
        for (int nt = 0; nt < 4; ++nt) {
            int n = wn * 64 + nt * 16 + lm;
            float bsn = b1[n];
#pragma unroll
            for (int r = 0; r < 4; ++r) {
                int row = wm * 16 + kgrp * 4 + r;
                float v = fmaxf(acc[nt][r] + bsn, 0.f);
                Mid[row * 128 + ((n >> 3) ^ (row & 15)) * 8 + (n & 7)] = f2bf(v);
            }
        }
    }
    __syncthreads();   // all Ws(w1) reads + Mid writes done

    // stage w2
#pragma unroll
    for (int i = 0; i < 8; ++i) {
        int idx = tid + i * 256;
        int n = idx >> 4, sc = idx & 15;
        gload16(w2t + (size_t)n * 128 + ((sc ^ (n & 15)) * 8), Ws + idx * 8);
    }
    __syncthreads();   // Ws(w2) staged

    // GEMM3: x W2 + b2 + Hm -> outp
    {
        f32x4 acc[4];
#pragma unroll
        for (int nt = 0; nt < 4; ++nt) acc[nt] = (f32x4)0.f;
#pragma unroll
        for (int kc = 0; kc < 4; ++kc) {
            int c = kc * 4 + kgrp;
            int r = wm * 16 + lm;
            bf16x8 af = *(const bf16x8*)(Mid + (r * 16 + (c ^ (r & 15))) * 8);
#pragma unroll
            for (int nt = 0; nt < 4; ++nt) {
                int n = wn * 64 + nt * 16 + lm;
                bf16x8 bfv = *(const bf16x8*)(Ws + (n * 16 + (c ^ (n & 15))) * 8);
                acc[nt] = __builtin_amdgcn_mfma_f32_16x16x32_bf16(af, bfv, acc[nt], 0, 0, 0);
            }
        }
#pragma unroll
        for (int nt = 0; nt < 4; ++nt) {
            int n = wn * 64 + nt * 16 + lm;
            float bsn = b2[n];
#pragma unroll
            for (int r = 0; r < 4; ++r) {
                int row = wm * 16 + kgrp * 4 + r;
                outp[((size_t)m0 + row) * 128 + n] =
                    acc[nt][r] + bsn + Hm[row * 128 + n];
            }
        }
    }
}

// ---------------------------------------------------------------------------
// Kernel 5 v7: swapped QK^T + double-buffered P-bounce (software-pipelined).
// Per kc: read P(kc)/V(kc) -> pack+write P(kc+1) into other buffer -> MFMA.
// Write->read of each P chunk is separated by a full iteration (exp/cvtpk
// VALU + MFMA) instead of being adjacent; per-wave DS ops complete in order
// so same-address write->read needs no barrier; compiler inserts the
// read->MFMA lgkmcnt waits. All manual waits/barriers removed.
// LDS: Kpad 32K + Vt 13.6K + Ptmp 20K = 66 KB -> 2 blocks/CU.
// ---------------------------------------------------------------------------
#define KS 40
#define VS 424
#define PSZ (16 * KS)
__global__ __launch_bounds__(512) void k_attn_mfma(
        const unsigned short* __restrict__ qb,
        const unsigned short* __restrict__ kb,
        const unsigned short* __restrict__ vb,
        unsigned short* __restrict__ out) {
    __shared__ __align__(16) unsigned short Kpad[400 * KS];
    __shared__ __align__(16) unsigned short Vt[16 * VS];
    __shared__ __align__(16) unsigned short Ptmp[8][2 * PSZ];
    int tid = threadIdx.x;
    int b = blockIdx.x & 63, h = blockIdx.x >> 6;   // XCD-grouping swizzle
    int lane = tid & 63, wave = tid >> 6;
    int lm = lane & 15, g = lane >> 4;

    for (int idx = tid; idx < 800; idx += 512) {
        int l = idx >> 1, half = idx & 1;
        ushort8 kv = *(const ushort8*)(kb + ((size_t)(b * 400 + l)) * 128 + h * 16 + half * 8);
        *(ushort8*)(Kpad + l * KS + half * 8) = kv;
        *(ushort8*)(Kpad + l * KS + 16 + half * 8) = (ushort8)0;
    }
    for (int idx = tid; idx < 800; idx += 512) {
        int kk = idx >> 1, dh = idx & 1;
        ushort8 vv = *(const ushort8*)(vb + ((size_t)(b * 400 + kk)) * 128 + h * 16 + dh * 8);
#pragma unroll
        for (int j = 0; j < 8; ++j) Vt[(dh * 8 + j) * VS + kk] = vv[j];
    }
    if (tid < 256) {
        int d = tid >> 4, kk = 400 + (tid & 15);
        Vt[d * VS + kk] = 0;
    }
    __syncthreads();

    unsigned short* Pw = Ptmp[wave];
    for (int tt = wave; tt < 25; tt += 8) {
        int q0 = tt * 16;
        bf16x8 Qf = *(const bf16x8*)(qb + ((size_t)(b * 400 + q0 + lm)) * 128 + h * 16 + g * 8);
        f32x4 s[25];
        __builtin_amdgcn_s_setprio(1);
#pragma unroll
        for (int kt = 0; kt < 25; ++kt) {
            bf16x8 Kf = *(const bf16x8*)(Kpad + (kt * 16 + lm) * KS + g * 8);
            s[kt] = __builtin_amdgcn_mfma_f32_16x16x32_bf16(Kf, Qf, (f32x4)0.f, 0, 0, 0);
        }
        __builtin_amdgcn_s_setprio(0);
        float m = -1e30f;
#pragma unroll
        for (int kt = 0; kt < 25; ++kt)
            m = fmaxf(m, fmaxf(fmaxf(s[kt][0], s[kt][1]),
                               fmaxf(s[kt][2], s[kt][3])));
        m = fmaxf(m, __shfl_xor(m, 16));
        m = fmaxf(m, __shfl_xor(m, 32));

        f32x4 O = (f32x4)0.f;
        f32x4 sumv = (f32x4)0.f;

        // prologue: pack + write P(0) into buffer 0
        {
            f32x4 p;
            p[0] = __expf(s[0][0] - m);
            p[1] = __expf(s[0][1] - m);
            p[2] = __expf(s[0][2] - m);
            p[3] = __expf(s[0][3] - m);
            sumv += p;
            uint2 w; w.x = cvtpk_bf16(p[0], p[1]); w.y = cvtpk_bf16(p[2], p[3]);
            *(uint2*)(Pw + lm * KS + g * 4) = w;
            f32x4 p2;
            p2[0] = __expf(s[1][0] - m);
            p2[1] = __expf(s[1][1] - m);
            p2[2] = __expf(s[1][2] - m);
            p2[3] = __expf(s[1][3] - m);
            sumv += p2;
            uint2 w2; w2.x = cvtpk_bf16(p2[0], p2[1]); w2.y = cvtpk_bf16(p2[2], p2[3]);
            *(uint2*)(Pw + lm * KS + 16 + g * 4) = w2;
        }

#pragma unroll
        for (int kc = 0; kc < 13; ++kc) {
            unsigned short* cur = Pw + (kc & 1) * PSZ;
            // read current P + V fragments (P(kc) written last iteration;
            // per-wave DS in-order guarantees the data is ordered correctly)
            bf16x8 Pf = *(const bf16x8*)(cur + lm * KS + g * 8);
            bf16x8 Vf = *(const bf16x8*)(Vt + lm * VS + kc * 32 + g * 8);
            // pack + write P(kc+1) into the other buffer (overlaps read latency)
            if (kc < 12) {
                unsigned short* nxt = Pw + ((kc + 1) & 1) * PSZ;
                {
                    int kt = 2 * (kc + 1);
                    f32x4 p;
                    p[0] = __expf(s[kt][0] - m);
                    p[1] = __expf(s[kt][1] - m);
                    p[2] = __expf(s[kt][2] - m);
                    p[3] = __expf(s[kt][3] - m);
                    sumv += p;
                    uint2 w; w.x = cvtpk_bf16(p[0], p[1]); w.y = cvtpk_bf16(p[2], p[3]);
                    *(uint2*)(nxt + lm * KS + g * 4) = w;
                }
                {
                    int kt = 2 * (kc + 1) + 1;
                    uint2 w; w.x = 0u; w.y = 0u;
                    if (kt < 25) {
                        f32x4 p;
                        p[0] = __expf(s[kt][0] - m);
                        p[1] = __expf(s[kt][1] - m);
                        p[2] = __expf(s[kt][2] - m);
                        p[3] = __expf(s[kt][3] - m);
                        sumv += p;
                        w.x = cvtpk_bf16(p[0], p[1]); w.y = cvtpk_bf16(p[2], p[3]);
                    }
                    *(uint2*)(nxt + lm * KS + 16 + g * 4) = w;
                }
            }
            O = __builtin_amdgcn_mfma_f32_16x16x32_bf16(Pf, Vf, O, 0, 0, 0);
        }
        float sum = (sumv[0] + sumv[1]) + (sumv[2] + sumv[3]);
        sum += __shfl_xor(sum, 16);
        sum += __shfl_xor(sum, 32);
        float rinv = 1.f / sum;
#pragma unroll
        for (int r = 0; r < 4; ++r) {
            float rq = __shfl(rinv, g * 4 + r);
            int q = q0 + g * 4 + r;
            out[((size_t)(b * 400 + q)) * 128 + h * 16 + lm] = f2bf(O[r] * rq);
        }
    }
}

// ---------------------------------------------------------------------------
extern "C" void kernel_launch(void* const* d_in, const int* in_sizes, int n_in,
                              void* d_out, int out_size, void* d_ws, size_t ws_size,
                              hipStream_t stream) {
    (void)in_sizes; (void)n_in; (void)out_size; (void)ws_size;
    const float* x      = (const float*)d_in[0];
    const float* w_init = (const float*)d_in[1];
    const float* b_init = (const float*)d_in[2];
    const float* lncg   = (const float*)d_in[3];
    const float* lncb   = (const float*)d_in[4];
    const float* w_dw   = (const float*)d_in[5];
    const float* b_dw   = (const float*)d_in[6];
    const float* w_pw   = (const float*)d_in[7];
    const float* b_pw   = (const float*)d_in[8];
    const float* lnag   = (const float*)d_in[9];
    const float* lnab   = (const float*)d_in[10];
    const float* wq     = (const float*)d_in[11];
    const float* bq     = (const float*)d_in[12];
    const float* wk     = (const float*)d_in[13];
    const float* bk     = (const float*)d_in[14];
    const float* wv     = (const float*)d_in[15];
    const float* bv     = (const float*)d_in[16];
    const float* wo     = (const float*)d_in[17];
    const float* bo     = (const float*)d_in[18];
    const float* lnfg   = (const float*)d_in[19];
    const float* lnfb   = (const float*)d_in[20];
    const float* w1     = (const float*)d_in[21];
    const float* b1     = (const float*)d_in[22];
    const float* w2     = (const float*)d_in[23];
    const float* b2     = (const float*)d_in[24];

    float* ws = (float*)d_ws;
    const size_t NBL = (size_t)BL * D;
    float* h0 = ws;
    float* outp = (float*)d_out;

    unsigned short* hnb = (unsigned short*)(ws + NBL);
    unsigned short* t0b = hnb + NBL;
    unsigned short* qb  = t0b + NBL;
    unsigned short* kb  = qb + NBL;
    unsigned short* vb  = kb + NBL;
    unsigned short* wt  = vb + NBL;
    unsigned short* xb  = wt + 10 * 16384;
    unsigned short* wbt = xb + (size_t)64 * 404 * 512;
    float* h1 = (float*)(wbt + (size_t)5 * 128 * 512);   // ping-pong buffer

    // merged pre-pass (x cvt + w_init cvt + 10x weight transpose)
    k_cvt_all<<<8384, 256, 0, stream>>>(x, xb, w_init, wbt,
                                        w_pw, wq, wk, wv, wo, w1, w2, wt);

    // 1) init conv + posenc
    k_initconv_mfma<<<640, 256, 0, stream>>>(xb, wbt, b_init, h0);

    // 2) 4x fused conv blocks, ping-pong h0 <-> h1
    for (int i = 0; i < NCONV; ++i) {
        const float* hin = (i & 1) ? h1 : h0;
        float* hout      = (i & 1) ? h0 : h1;
        k_convblock<<<832, 256, 0, stream>>>(
            hin, hout, lncg + i * D, lncb + i * D,
            w_dw + (size_t)i * 7 * D, b_dw + i * D,
            wt + (size_t)i * 16384, b_pw + i * D);
    }

    // 3) attention: fused LN + QKV (one A-stage, three weights)
    k_ln_gemm<<<800, 256, 0, stream>>>(h0, lnag, lnab, wt + 4 * 16384, 3,
                                       bq, bk, bv, qb, kb, vb, 0.25f, 0);
    k_attn_mfma<<<512, 512, 0, stream>>>(qb, kb, vb, t0b);

    // 4) fused o-proj + residual + FFN -> out
    k_oproj_ffn<<<800, 256, 0, stream>>>(
        t0b, h0, wt + 7 * 16384, bo, lnfg, lnfb,
        wt + 8 * 16384, b1, wt + 9 * 16384, b2, outp);
}